// Round 7
// baseline (747.812 us; speedup 1.0000x reference)
//
#include <hip/hip_runtime.h>
#include <math.h>

#define NN 100000
#define EE 800000
#define IN_DIM 128
#define HID 32
#define HEADS 4
#define QKV 128         // HEADS*HID
#define COLS 416        // 3*QKV + HID (q|k|v|skip)
#define QBH_W 128       // q bf16 row (256 B)
#define SB_W 32         // skip fp32 row (128 B)
#define KV_W 256        // interleaved bf16: 32 groups of [k x4 | v x4] (512-B rows)
#define OUT_DIM 16
#define NTILE 26        // 416/16 col-tiles
#define NBK 782         // ceil(NN/128) dst-buckets
// (1/sqrt(32)) * log2(e): pre-folded into q so p = exp2(part)
#define QSCALE 0.25503512f

typedef __attribute__((ext_vector_type(8))) short short8;
typedef __attribute__((ext_vector_type(4))) float floatx4;

__device__ __forceinline__ unsigned short f2bf(float f) {
    unsigned int u = __float_as_uint(f);
    unsigned int r = (u + 0x7FFF + ((u >> 16) & 1)) >> 16;   // RNE
    return (unsigned short)r;
}
__device__ __forceinline__ float bf2f(unsigned short h) {
    return __uint_as_float((unsigned int)h << 16);
}
__device__ __forceinline__ float bf_lo(unsigned int d) {
    return __uint_as_float(d << 16);
}
__device__ __forceinline__ float bf_hi(unsigned int d) {
    return __uint_as_float(d & 0xFFFF0000u);
}

// ---------------- fragment-pack BOTH layers' W (split hi/lo) + biases ----
// Wf[((c*26 + t)*64 + lane)*8 + j] = W[(c*32 + (lane>>4)*8 + j)][t*16 + (lane&15)]
__device__ __forceinline__ void pack_one(
        const float* __restrict__ Wq, const float* __restrict__ Wk,
        const float* __restrict__ Wv, const float* __restrict__ Ws,
        const float* __restrict__ bq, const float* __restrict__ bk,
        const float* __restrict__ bv, const float* __restrict__ bs,
        unsigned short* __restrict__ Wfh, unsigned short* __restrict__ Wfl,
        float* __restrict__ bp, int K, int idx) {
    if (idx < COLS) {
        float b;
        if (idx < 128)      b = bq[idx];
        else if (idx < 256) b = bk[idx - 128];
        else if (idx < 384) b = bv[idx - 256];
        else                b = bs[idx - 384];
        bp[idx] = b;
    }
    int nch = K >> 5;
    if (idx >= nch * NTILE * 64) return;
    int lane = idx & 63;
    int tt = (idx >> 6) % NTILE;
    int c = idx / (NTILE * 64);
    int k0 = c * 32 + (lane >> 4) * 8;
    int col = tt * 16 + (lane & 15);
    #pragma unroll
    for (int j = 0; j < 8; ++j) {
        int k = k0 + j;
        float w;
        if (col < 128)      w = Wq[(size_t)k * 128 + col];
        else if (col < 256) w = Wk[(size_t)k * 128 + (col - 128)];
        else if (col < 384) w = Wv[(size_t)k * 128 + (col - 256)];
        else                w = Ws[(size_t)k * 32 + (col - 384)];
        unsigned short hi = f2bf(w);
        float rem = w - bf2f(hi);
        Wfh[(size_t)idx * 8 + j] = hi;
        Wfl[(size_t)idx * 8 + j] = f2bf(rem);
    }
}

__global__ void pack_frag2(
        const float* __restrict__ Wq0, const float* __restrict__ Wk0,
        const float* __restrict__ Wv0, const float* __restrict__ Ws0,
        const float* __restrict__ bq0, const float* __restrict__ bk0,
        const float* __restrict__ bv0, const float* __restrict__ bs0,
        const float* __restrict__ Wq1, const float* __restrict__ Wk1,
        const float* __restrict__ Wv1, const float* __restrict__ Ws1,
        const float* __restrict__ bq1, const float* __restrict__ bk1,
        const float* __restrict__ bv1, const float* __restrict__ bs1,
        unsigned short* __restrict__ Wf0h, unsigned short* __restrict__ Wf0l,
        float* __restrict__ bp0,
        unsigned short* __restrict__ Wf1h, unsigned short* __restrict__ Wf1l,
        float* __restrict__ bp1) {
    const int L0N = 4 * NTILE * 64;   // 6656
    int gid = blockIdx.x * blockDim.x + threadIdx.x;
    if (gid < L0N) {
        pack_one(Wq0, Wk0, Wv0, Ws0, bq0, bk0, bv0, bs0, Wf0h, Wf0l, bp0, 128, gid);
    } else {
        pack_one(Wq1, Wk1, Wv1, Ws1, bq1, bk1, bv1, bs1, Wf1h, Wf1l, bp1, 32, gid - L0N);
    }
}

// ---------------- fp32 -> split bf16 (hi + lo residual) ----------------
__global__ void to_bf16_split(const float* __restrict__ X,
                              unsigned short* __restrict__ Xh,
                              unsigned short* __restrict__ Xl, int total4) {
    int i = blockIdx.x * blockDim.x + threadIdx.x;
    if (i >= total4) return;
    int i4 = i * 4;
    float4 v = *(const float4*)(X + i4);
    ushort4 h = {f2bf(v.x), f2bf(v.y), f2bf(v.z), f2bf(v.w)};
    ushort4 l = {f2bf(v.x - bf2f(h.x)), f2bf(v.y - bf2f(h.y)),
                 f2bf(v.z - bf2f(h.z)), f2bf(v.w - bf2f(h.w))};
    *(ushort4*)(Xh + i4) = h;
    *(ushort4*)(Xl + i4) = l;
}

// ---------------- CSR build: bucket-locality counting sort ---------------
// R18: replace {NN-wide hist + 3-kernel scan + random 4B scatter (~60-70us
// of 16x write-amplified traffic, measured via R17's scatter_by_src)} with
// a 2-level bucket sort. Bucket = dst>>7 (128 dsts, ~1024 edges each).
// Phase writes stay inside per-bucket windows -> L2 write-combines.

// hist over 782 buckets
__global__ void bucket_hist(const int* __restrict__ ei, int* __restrict__ bh) {
    int e = blockIdx.x * blockDim.x + threadIdx.x;
    if (e < EE) atomicAdd(&bh[ei[EE + e] >> 7], 1);
}

// single-block scan of the 782 bucket counts -> bbase (excl, 783 entries)
// and bcurs (working copy for the scatter)
__global__ void bucket_scan(const int* __restrict__ bh, int* __restrict__ bbase,
                            int* __restrict__ bcurs) {
    __shared__ int s1[1024];
    int t = threadIdx.x;   // 1024 threads
    s1[t] = (t < NBK) ? bh[t] : 0;
    __syncthreads();
    for (int off = 1; off < 1024; off <<= 1) {
        int v = (t >= off) ? s1[t - off] : 0;
        __syncthreads();
        s1[t] += v;
        __syncthreads();
    }
    // inclusive -> exclusive
    int excl = (t == 0) ? 0 : s1[t - 1];
    if (t <= NBK) bbase[t] = (t == NBK) ? s1[NBK - 1] : excl;
    if (t < NBK) bcurs[t] = excl;
}

// scatter (src,dst) pairs into bucket regions (write frontier per bucket)
__global__ void bucket_scatter(const int* __restrict__ ei, int* __restrict__ bcurs,
                               int2* __restrict__ pairs) {
    int e = blockIdx.x * blockDim.x + threadIdx.x;
    if (e < EE) {
        int s = ei[e];
        int d = ei[EE + e];
        int pos = atomicAdd(&bcurs[d >> 7], 1);
        pairs[pos] = make_int2(s, d);
    }
}

// one block per bucket: LDS histogram+scan of the 128 local dsts, emit
// per-dst roff and the final dst-grouped esrc (writes confined to the
// bucket's ~4KB window).
__global__ __launch_bounds__(256) void bucket_sort(
        const int2* __restrict__ pairs, const int* __restrict__ bbase,
        int* __restrict__ roff, int* __restrict__ esrc) {
    __shared__ int hist[128], incl[128], curs[128];
    const int b = blockIdx.x;
    const int t = threadIdx.x;
    const int base = bbase[b];
    const int cnt = bbase[b + 1] - base;
    if (t < 128) hist[t] = 0;
    __syncthreads();
    for (int i = t; i < cnt; i += 256)
        atomicAdd(&hist[pairs[base + i].y & 127], 1);
    __syncthreads();
    if (t < 128) incl[t] = hist[t];
    __syncthreads();
    for (int off = 1; off < 128; off <<= 1) {
        int v = (t < 128 && t >= off) ? incl[t - off] : 0;
        __syncthreads();
        if (t < 128) incl[t] += v;
        __syncthreads();
    }
    if (t < 128) {
        int excl = incl[t] - hist[t];
        curs[t] = excl;
        int dst = (b << 7) + t;
        if (dst < NN) roff[dst] = base + excl;
    }
    __syncthreads();
    for (int i = t; i < cnt; i += 256) {
        int2 p = pairs[base + i];
        int pos = atomicAdd(&curs[p.y & 127], 1);
        esrc[base + pos] = p.x;
    }
    if (b == NBK - 1 && t == 0) roff[NN] = EE;
}

// ---------------- split-precision MFMA GEMM, X staged once in LDS --------
// R15: one block = 128 rows x ALL 26 col-tiles. X (hi+lo) loaded from
// global exactly ONCE per block into XOR-swizzled LDS. Each wave owns 32
// rows and loops over ALL 7 groups.
template <int NCH>
__global__ __launch_bounds__(256, 2) void gemm_mfma(
        const unsigned short* __restrict__ Xh, const unsigned short* __restrict__ Xl,
        const unsigned short* __restrict__ Wfh, const unsigned short* __restrict__ Wfl,
        const float* __restrict__ bp, unsigned short* __restrict__ qbh,
        float* __restrict__ sb, unsigned short* __restrict__ kvb) {
    constexpr int K = NCH * 32;
    constexpr int ROWB = 2 * K;              // bytes per X row (bf16)
    constexpr int SWZ = (NCH == 4) ? 7 : 3;  // row-XOR mask (<<4)
    __shared__ char xlds[2 * 128 * ROWB];    // hi plane then lo plane
    __shared__ char olds[4][32][128];        // per-wave out staging
    const int tid = threadIdx.x;
    const int lane = tid & 63;
    const int wv = tid >> 6;
    const int m0b = blockIdx.x << 7;         // block's 128-row base
    const int ml = lane & 15;
    const int quad = lane >> 4;

    // ---- stage X hi+lo into LDS (coalesced 16B pieces, XOR-swizzled) ----
    {
        const int NP = 128 * ROWB / 16;      // pieces per plane
        const char* gsrc[2] = { (const char*)Xh, (const char*)Xl };
        #pragma unroll
        for (int pl = 0; pl < 2; ++pl) {
            char* dstp = xlds + (size_t)pl * 128 * ROWB;
            for (int p = tid; p < NP; p += 256) {
                int gb = p * 16;
                int row = gb / ROWB;
                int col = gb & (ROWB - 1);
                int grow = m0b + row;
                if (grow >= NN) grow = NN - 1;
                uint4 d = *(const uint4*)(gsrc[pl] + (size_t)grow * ROWB + col);
                *(uint4*)(dstp + row * ROWB + (col ^ ((row & SWZ) << 4))) = d;
            }
        }
    }
    __syncthreads();

    const int m0 = m0b + (wv << 5);          // this wave's 32-row base
    const int rowL0 = (wv << 5) + ml;        // local row, half 0
    const int rowL1 = rowL0 + 16;            // local row, half 1
    char* myl = &olds[wv][0][0];

    // each wave: its 32 rows x ALL 7 column groups
    for (int g = 0; g < 7; ++g) {
        int tiles[4]; int ntl = 4; int gtype;     // 0=q, 1=kv, 2=skip
        if (g < 2) {
            gtype = 0;
            #pragma unroll
            for (int i = 0; i < 4; ++i) tiles[i] = 4 * g + i;
        } else if (g < 6) {
            gtype = 1;
            int j = g - 2;
            tiles[0] = 8 + 2 * j; tiles[1] = 9 + 2 * j;
            tiles[2] = 16 + 2 * j; tiles[3] = 17 + 2 * j;
        } else {
            gtype = 2; ntl = 2;
            tiles[0] = 24; tiles[1] = 25; tiles[2] = 24; tiles[3] = 25;
        }

        floatx4 acc[2][4] = {};

        #pragma unroll
        for (int c = 0; c < NCH; ++c) {
            int colb = (c * 64 + quad * 16);
            int a0 = rowL0 * ROWB + (colb ^ ((rowL0 & SWZ) << 4));
            int a1 = rowL1 * ROWB + (colb ^ ((rowL1 & SWZ) << 4));
            short8 x0h = *(const short8*)(xlds + a0);
            short8 x1h = *(const short8*)(xlds + a1);
            short8 x0l = *(const short8*)(xlds + 128 * ROWB + a0);
            short8 x1l = *(const short8*)(xlds + 128 * ROWB + a1);
            #pragma unroll
            for (int t = 0; t < 4; ++t) {
                if (t < ntl) {
                    size_t boff = (((size_t)c * NTILE + tiles[t]) * 64 + lane) * 8;
                    short8 wh = *(const short8*)(Wfh + boff);
                    short8 wl = *(const short8*)(Wfl + boff);
                    acc[0][t] = __builtin_amdgcn_mfma_f32_16x16x32_bf16(wh, x0h, acc[0][t], 0, 0, 0);
                    acc[0][t] = __builtin_amdgcn_mfma_f32_16x16x32_bf16(wl, x0h, acc[0][t], 0, 0, 0);
                    acc[0][t] = __builtin_amdgcn_mfma_f32_16x16x32_bf16(wh, x0l, acc[0][t], 0, 0, 0);
                    acc[1][t] = __builtin_amdgcn_mfma_f32_16x16x32_bf16(wh, x1h, acc[1][t], 0, 0, 0);
                    acc[1][t] = __builtin_amdgcn_mfma_f32_16x16x32_bf16(wl, x1h, acc[1][t], 0, 0, 0);
                    acc[1][t] = __builtin_amdgcn_mfma_f32_16x16x32_bf16(wh, x1l, acc[1][t], 0, 0, 0);
                }
            }
        }

        // ---- stage into wave-private LDS in FINAL byte order (XOR pitch-128) ----
        #pragma unroll
        for (int t = 0; t < 4; ++t) {
            if (t >= ntl) break;
            int tg = tiles[t];
            int c0 = (tg << 4) + (quad << 2);
            float4 b4 = *(const float4*)(bp + c0);
            #pragma unroll
            for (int mt = 0; mt < 2; ++mt) {
                int row = mt * 16 + ml;
                int sz = (row & 7) << 4;
                float v0 = acc[mt][t][0] + b4.x;
                float v1 = acc[mt][t][1] + b4.y;
                float v2 = acc[mt][t][2] + b4.z;
                float v3 = acc[mt][t][3] + b4.w;
                if (gtype == 2) {                  // skip fp32
                    *(float4*)(myl + row * 128 + ((64 * t + 16 * quad) ^ sz)) =
                        make_float4(v0, v1, v2, v3);
                } else {
                    ushort4 u = {f2bf(v0), f2bf(v1), f2bf(v2), f2bf(v3)};
                    int off;
                    if (gtype == 0) off = 32 * t + 8 * quad;                 // q linear
                    else off = 64 * (t & 1) + 16 * quad + 8 * (t >> 1);      // kv interleave
                    *(ushort4*)(myl + row * 128 + (off ^ sz)) = u;
                }
            }
        }
        // wave-private RAW/WAR: DS pipe is in-order per wave; compiler
        // inserts lgkmcnt waits. No barrier needed.

        // ---- linear read-back + full-line global stores ----
        const int lr = lane >> 3;          // 0..7 row within page
        const int lc = (lane & 7) * 16;    // byte offset in 128-B chunk
        #pragma unroll
        for (int i = 0; i < 4; ++i) {
            int row = i * 8 + lr;
            uint4 d = *(const uint4*)(myl + row * 128 + (lc ^ (lr << 4)));
            int node = m0 + row;
            if (node < NN) {
                char* dst;
                if (gtype == 0)      dst = (char*)qbh + (size_t)node * 256 + g * 128 + lc;
                else if (gtype == 1) dst = (char*)kvb + (size_t)node * 512 + (g - 2) * 128 + lc;
                else                 dst = (char*)sb + (size_t)node * 128 + lc;
                *(uint4*)dst = d;
            }
        }
    }
}

// ---------------- fused attention: ONE NODE PER HALF-WAVE ----------------
// R16 structure (best so far): wave = 2 nodes, 8 independent gathers in
// flight per wave. NO-MAX softmax (logits bounded, fp32 exact).
#define ATTN_STEP(u) {                                                       \
    float k0 = bf_lo((u).x), k1 = bf_hi((u).x);                              \
    float k2 = bf_lo((u).y), k3 = bf_hi((u).y);                              \
    float v0 = bf_lo((u).z), v1 = bf_hi((u).z);                              \
    float v2 = bf_lo((u).w), v3 = bf_hi((u).w);                              \
    float part = q4.x * k0 + q4.y * k1 + q4.z * k2 + q4.w * k3;              \
    part += __shfl_xor(part, 1);                                             \
    part += __shfl_xor(part, 2);                                             \
    part += __shfl_xor(part, 4);                                             \
    float p = exp2f(part);                                                   \
    s += p;                                                                  \
    acc.x += p * v0;                                                         \
    acc.y += p * v1;                                                         \
    acc.z += p * v2;                                                         \
    acc.w += p * v3; }

__global__ __launch_bounds__(256) void fused_attn(
        const unsigned short* __restrict__ qbh, const float* __restrict__ sb,
        const unsigned short* __restrict__ kvb,
        const int* __restrict__ roff, const int* __restrict__ esrc,
        float* __restrict__ hout,
        unsigned short* __restrict__ hh, unsigned short* __restrict__ hl) {
    const int lane = threadIdx.x & 63;
    const int w = (blockIdx.x * blockDim.x + threadIdx.x) >> 6;   // wave id
    const int hw = lane >> 5;
    const int n = 2 * w + hw;          // this half-wave's node
    if (n >= NN) return;               // NN even: whole halves retire
    const int kl = lane & 31;

    ushort4 qu = *(const ushort4*)(qbh + (size_t)n * QBH_W + 4 * kl);
    float4 q4 = make_float4(bf2f(qu.x) * QSCALE, bf2f(qu.y) * QSCALE,
                            bf2f(qu.z) * QSCALE, bf2f(qu.w) * QSCALE);
    // hoist skip row (redundant 4x read, coalesced, overlaps gather loop)
    float4 sk = *(const float4*)(sb + (size_t)n * SB_W + 4 * (kl & 7));

    float s = 0.f;
    float4 acc = make_float4(0.f, 0.f, 0.f, 0.f);
    const int e0 = roff[n];
    const int cnt = roff[n + 1] - e0;
    int i = 0;
    for (; i + 4 <= cnt; i += 4) {
        int b0 = esrc[e0 + i];
        int b1 = esrc[e0 + i + 1];
        int b2 = esrc[e0 + i + 2];
        int b3 = esrc[e0 + i + 3];
        uint4 u0 = *(const uint4*)(kvb + (size_t)b0 * KV_W + 8 * kl);
        uint4 u1 = *(const uint4*)(kvb + (size_t)b1 * KV_W + 8 * kl);
        uint4 u2 = *(const uint4*)(kvb + (size_t)b2 * KV_W + 8 * kl);
        uint4 u3 = *(const uint4*)(kvb + (size_t)b3 * KV_W + 8 * kl);
        ATTN_STEP(u0); ATTN_STEP(u1); ATTN_STEP(u2); ATTN_STEP(u3);
    }
    for (; i < cnt; ++i) {
        int b0 = esrc[e0 + i];
        uint4 u0 = *(const uint4*)(kvb + (size_t)b0 * KV_W + 8 * kl);
        ATTN_STEP(u0);
    }

    float inv = (s > 0.f) ? 1.f / s : 0.f;
    float4 o;
    o.x = acc.x * inv; o.y = acc.y * inv; o.z = acc.z * inv; o.w = acc.w * inv;
    // sum over heads (head bits of kl are bits 3,4; xor 8/16 stay in-half)
    o.x += __shfl_xor(o.x, 8);  o.y += __shfl_xor(o.y, 8);  o.z += __shfl_xor(o.z, 8);  o.w += __shfl_xor(o.w, 8);
    o.x += __shfl_xor(o.x, 16); o.y += __shfl_xor(o.y, 16); o.z += __shfl_xor(o.z, 16); o.w += __shfl_xor(o.w, 16);
    if (kl < 8) {
        float4 rr;
        rr.x = fmaxf(o.x * 0.25f + sk.x, 0.f);
        rr.y = fmaxf(o.y * 0.25f + sk.y, 0.f);
        rr.z = fmaxf(o.z * 0.25f + sk.z, 0.f);
        rr.w = fmaxf(o.w * 0.25f + sk.w, 0.f);
        int c0 = 4 * kl;
        if (hout)
            *(float4*)(hout + (size_t)n * HID + c0) = rr;
        if (hh) {
            ushort4 uh = {f2bf(rr.x), f2bf(rr.y), f2bf(rr.z), f2bf(rr.w)};
            ushort4 ul = {f2bf(rr.x - bf2f(uh.x)), f2bf(rr.y - bf2f(uh.y)),
                          f2bf(rr.z - bf2f(uh.z)), f2bf(rr.w - bf2f(uh.w))};
            *(ushort4*)(hh + (size_t)n * HID + c0) = uh;
            *(ushort4*)(hl + (size_t)n * HID + c0) = ul;
        }
    }
}

// ---------------- final linear: out = h @ Wout + bout --------------------
__global__ void out_linear(const float* __restrict__ h, const float* __restrict__ Wout,
                           const float* __restrict__ bout, float* __restrict__ out) {
    int idx = blockIdx.x * blockDim.x + threadIdx.x;
    if (idx >= NN * OUT_DIM) return;
    int n = idx >> 4;
    int j = idx & 15;
    float accv = bout[j];
    #pragma unroll
    for (int k = 0; k < HID; ++k)
        accv += h[(size_t)n * HID + k] * Wout[k * OUT_DIM + j];
    out[idx] = accv;
}

extern "C" void kernel_launch(void* const* d_in, const int* in_sizes, int n_in,
                              void* d_out, int out_size, void* d_ws, size_t ws_size,
                              hipStream_t stream) {
    const float* x  = (const float*)d_in[0];
    const int*   ei = (const int*)d_in[1];
    const float* l0w[8]; const float* l1w[8];
    for (int i = 0; i < 8; ++i) { l0w[i] = (const float*)d_in[2 + i]; l1w[i] = (const float*)d_in[10 + i]; }
    const float* Wout = (const float*)d_in[18];
    const float* bout = (const float*)d_in[19];
    float* out = (float*)d_out;

    // workspace layout
    float* ws = (float*)d_ws;
    float* sb   = ws;                           // NN*32 floats
    float* h0   = sb + (size_t)NN * SB_W;       // NN*32
    float* bp0  = h0 + (size_t)NN * HID;        // 416
    float* bp1  = bp0 + COLS;                   // 416
    unsigned short* qbh  = (unsigned short*)(bp1 + COLS);    // NN*128 bf16
    unsigned short* kvb  = qbh + (size_t)NN * QBH_W;         // NN*256 bf16
    unsigned short* xh   = kvb + (size_t)NN * KV_W;          // NN*128
    unsigned short* xl   = xh + (size_t)NN * IN_DIM;         // NN*128
    unsigned short* hh   = xl + (size_t)NN * IN_DIM;         // NN*32
    unsigned short* hl   = hh + (size_t)NN * HID;            // NN*32
    unsigned short* Wf0h = hl + (size_t)NN * HID;            // 4*26*64*8
    unsigned short* Wf0l = Wf0h + 4 * NTILE * 64 * 8;
    unsigned short* Wf1h = Wf0l + 4 * NTILE * 64 * 8;        // 1*26*64*8
    unsigned short* Wf1l = Wf1h + NTILE * 64 * 8;
    int* ibase  = (int*)(Wf1l + NTILE * 64 * 8);
    int* roff    = ibase;                       // NN+1
    int* esrc    = roff + NN + 1;               // EE
    int* bh      = esrc + EE;                   // 784
    int* bbase   = bh + 784;                    // 784
    int* bcurs   = bbase + 784;                 // 784

    // pairs scratch ALIASED onto xh/xl (CSR build runs before to_bf16_split
    // in stream order, so lifetimes don't overlap)
    int2* pairs = (int2*)xh;                    // EE int2 (6.4 MB)

    // pack BOTH layers' weights in one launch
    pack_frag2<<<(5 * NTILE * 64 + 255) / 256, 256, 0, stream>>>(
        l0w[0], l0w[2], l0w[4], l0w[6], l0w[1], l0w[3], l0w[5], l0w[7],
        l1w[0], l1w[2], l1w[4], l1w[6], l1w[1], l1w[3], l1w[5], l1w[7],
        Wf0h, Wf0l, bp0, Wf1h, Wf1l, bp1);

    // ---- CSR build: bucket counting sort ----
    hipMemsetAsync(bh, 0, 784 * sizeof(int), stream);
    bucket_hist<<<(EE + 255) / 256, 256, 0, stream>>>(ei, bh);
    bucket_scan<<<1, 1024, 0, stream>>>(bh, bbase, bcurs);
    bucket_scatter<<<(EE + 255) / 256, 256, 0, stream>>>(ei, bcurs, pairs);
    bucket_sort<<<NBK, 256, 0, stream>>>(pairs, bbase, roff, esrc);

    // now safe to overwrite xh/xl
    to_bf16_split<<<(NN * IN_DIM / 4 + 255) / 256, 256, 0, stream>>>(x, xh, xl, NN * IN_DIM / 4);

    const int gemm_blocks = (NN + 127) / 128;    // 782, one block = 128 rows x all tiles
    const int attn_waves = (NN + 1) / 2;         // one node per half-wave
    const int attn_blocks = (attn_waves * 64 + 255) / 256;   // 12500

    // layer 0 (attn writes only hh/hl)
    gemm_mfma<4><<<gemm_blocks, 256, 0, stream>>>(xh, xl, Wf0h, Wf0l, bp0, qbh, sb, kvb);
    fused_attn<<<attn_blocks, 256, 0, stream>>>(qbh, sb, kvb, roff, esrc, (float*)nullptr, hh, hl);

    // layer 1 (attn writes only h0)
    gemm_mfma<1><<<gemm_blocks, 256, 0, stream>>>(hh, hl, Wf1h, Wf1l, bp1, qbh, sb, kvb);
    fused_attn<<<attn_blocks, 256, 0, stream>>>(qbh, sb, kvb, roff, esrc, h0,
                                                (unsigned short*)nullptr, (unsigned short*)nullptr);

    // output linear
    out_linear<<<(NN * OUT_DIM + 255) / 256, 256, 0, stream>>>(h0, Wout, bout, out);
}

// Round 8
// 443.987 us; speedup vs baseline: 1.6843x; 1.6843x over previous
//
#include <hip/hip_runtime.h>
#include <math.h>

#define NN 100000
#define EE 800000
#define IN_DIM 128
#define HID 32
#define HEADS 4
#define QKV 128         // HEADS*HID
#define COLS 416        // 3*QKV + HID (q|k|v|skip)
#define QBH_W 128       // q bf16 row (256 B)
#define SB_W 32         // skip fp32 row (128 B)
#define KV_W 256        // interleaved bf16: 32 groups of [k x4 | v x4] (512-B rows)
#define OUT_DIM 16
#define NB 98           // ceil(NN/1024) scan blocks
#define NTILE 26        // 416/16 col-tiles
#define NBIN 128        // dst-range bins for CSR sort
#define BINW 782        // ceil(NN/NBIN); 128*782 = 100096 >= NN
#define CH 2048         // edges per chunk
#define NCHUNK 391      // ceil(EE/CH)
// (1/sqrt(32)) * log2(e): pre-folded into q so p = exp2(part)
#define QSCALE 0.25503512f

typedef __attribute__((ext_vector_type(8))) short short8;
typedef __attribute__((ext_vector_type(4))) float floatx4;

__device__ __forceinline__ unsigned short f2bf(float f) {
    unsigned int u = __float_as_uint(f);
    unsigned int r = (u + 0x7FFF + ((u >> 16) & 1)) >> 16;   // RNE
    return (unsigned short)r;
}
__device__ __forceinline__ float bf2f(unsigned short h) {
    return __uint_as_float((unsigned int)h << 16);
}
__device__ __forceinline__ float bf_lo(unsigned int d) {
    return __uint_as_float(d << 16);
}
__device__ __forceinline__ float bf_hi(unsigned int d) {
    return __uint_as_float(d & 0xFFFF0000u);
}

// ---------------- fragment-pack BOTH layers' W (split hi/lo) + biases ----
// Wf[((c*26 + t)*64 + lane)*8 + j] = W[(c*32 + (lane>>4)*8 + j)][t*16 + (lane&15)]
__device__ __forceinline__ void pack_one(
        const float* __restrict__ Wq, const float* __restrict__ Wk,
        const float* __restrict__ Wv, const float* __restrict__ Ws,
        const float* __restrict__ bq, const float* __restrict__ bk,
        const float* __restrict__ bv, const float* __restrict__ bs,
        unsigned short* __restrict__ Wfh, unsigned short* __restrict__ Wfl,
        float* __restrict__ bp, int K, int idx) {
    if (idx < COLS) {
        float b;
        if (idx < 128)      b = bq[idx];
        else if (idx < 256) b = bk[idx - 128];
        else if (idx < 384) b = bv[idx - 256];
        else                b = bs[idx - 384];
        bp[idx] = b;
    }
    int nch = K >> 5;
    if (idx >= nch * NTILE * 64) return;
    int lane = idx & 63;
    int tt = (idx >> 6) % NTILE;
    int c = idx / (NTILE * 64);
    int k0 = c * 32 + (lane >> 4) * 8;
    int col = tt * 16 + (lane & 15);
    #pragma unroll
    for (int j = 0; j < 8; ++j) {
        int k = k0 + j;
        float w;
        if (col < 128)      w = Wq[(size_t)k * 128 + col];
        else if (col < 256) w = Wk[(size_t)k * 128 + (col - 128)];
        else if (col < 384) w = Wv[(size_t)k * 128 + (col - 256)];
        else                w = Ws[(size_t)k * 32 + (col - 384)];
        unsigned short hi = f2bf(w);
        float rem = w - bf2f(hi);
        Wfh[(size_t)idx * 8 + j] = hi;
        Wfl[(size_t)idx * 8 + j] = f2bf(rem);
    }
}

__global__ void pack_frag2(
        const float* __restrict__ Wq0, const float* __restrict__ Wk0,
        const float* __restrict__ Wv0, const float* __restrict__ Ws0,
        const float* __restrict__ bq0, const float* __restrict__ bk0,
        const float* __restrict__ bv0, const float* __restrict__ bs0,
        const float* __restrict__ Wq1, const float* __restrict__ Wk1,
        const float* __restrict__ Wv1, const float* __restrict__ Ws1,
        const float* __restrict__ bq1, const float* __restrict__ bk1,
        const float* __restrict__ bv1, const float* __restrict__ bs1,
        unsigned short* __restrict__ Wf0h, unsigned short* __restrict__ Wf0l,
        float* __restrict__ bp0,
        unsigned short* __restrict__ Wf1h, unsigned short* __restrict__ Wf1l,
        float* __restrict__ bp1) {
    const int L0N = 4 * NTILE * 64;   // 6656
    int gid = blockIdx.x * blockDim.x + threadIdx.x;
    if (gid < L0N) {
        pack_one(Wq0, Wk0, Wv0, Ws0, bq0, bk0, bv0, bs0, Wf0h, Wf0l, bp0, 128, gid);
    } else {
        pack_one(Wq1, Wk1, Wv1, Ws1, bq1, bk1, bv1, bs1, Wf1h, Wf1l, bp1, 32, gid - L0N);
    }
}

// ---------------- fp32 -> split bf16 (hi + lo residual) ----------------
__global__ void to_bf16_split(const float* __restrict__ X,
                              unsigned short* __restrict__ Xh,
                              unsigned short* __restrict__ Xl, int total4) {
    int i = blockIdx.x * blockDim.x + threadIdx.x;
    if (i >= total4) return;
    int i4 = i * 4;
    float4 v = *(const float4*)(X + i4);
    ushort4 h = {f2bf(v.x), f2bf(v.y), f2bf(v.z), f2bf(v.w)};
    ushort4 l = {f2bf(v.x - bf2f(h.x)), f2bf(v.y - bf2f(h.y)),
                 f2bf(v.z - bf2f(h.z)), f2bf(v.w - bf2f(h.w))};
    *(ushort4*)(Xh + i4) = h;
    *(ushort4*)(Xl + i4) = l;
}

// ---------------- CSR build: ATOMIC-FREE deterministic bin sort ----------
// R19 lesson (R17/R18 measured): per-element contended global atomics
// serialize (~12ns/op per cache line) and random small writes amplify
// 6-16x across non-coherent XCD L2s. This pipeline histograms in LDS,
// derives all global offsets deterministically, and makes every global
// write a coalesced run.

// one block per 2048-edge chunk: LDS 128-bin hist -> cmat row, plus
// per-dst degree (random atomics over 400KB -> low contention, cheap).
__global__ __launch_bounds__(256) void chunk_hist(
        const int* __restrict__ ei, int* __restrict__ deg,
        int* __restrict__ cmat) {
    __shared__ int cnt[NBIN];
    const int t = threadIdx.x;
    const int c = blockIdx.x;
    const int c0 = c * CH;
    const int nc = min(CH, EE - c0);
    if (t < NBIN) cnt[t] = 0;
    __syncthreads();
    for (int i = t; i < nc; i += 256) {
        int d = ei[EE + c0 + i];
        atomicAdd(&deg[d], 1);
        atomicAdd(&cnt[d / BINW], 1);
    }
    __syncthreads();
    if (t < NBIN) cmat[c * NBIN + t] = cnt[t];
}

__global__ void block_sum(const int* __restrict__ deg, int* __restrict__ partial) {
    __shared__ int sdata[256];
    int b = blockIdx.x, t = threadIdx.x;
    int sum = 0;
    for (int i = t; i < 1024; i += 256) {
        int g = b * 1024 + i;
        if (g < NN) sum += deg[g];
    }
    sdata[t] = sum; __syncthreads();
    for (int s = 128; s > 0; s >>= 1) {
        if (t < s) sdata[t] += sdata[t + s];
        __syncthreads();
    }
    if (t == 0) partial[b] = sdata[0];
}

// wave-parallel exclusive scan of the NB partials (NB <= 128)
__global__ void scan_partial(int* __restrict__ partial) {
    int l = threadIdx.x;   // 64 threads
    int a = (l < NB) ? partial[l] : 0;
    int b = (l + 64 < NB) ? partial[l + 64] : 0;
    for (int off = 1; off < 64; off <<= 1) {
        int v = __shfl_up(a, off);
        if (l >= off) a += v;
    }
    int tot = __shfl(a, 63);
    for (int off = 1; off < 64; off <<= 1) {
        int v = __shfl_up(b, off);
        if (l >= off) b += v;
    }
    b += tot;
    int ea = __shfl_up(a, 1); if (l == 0) ea = 0;
    int eb = __shfl_up(b, 1); if (l == 0) eb = tot;
    if (l < NB) partial[l] = ea;
    if (l + 64 < NB) partial[l + 64] = eb;
}

__global__ void block_scan(const int* __restrict__ deg, const int* __restrict__ partial,
                           int* __restrict__ roff, int* __restrict__ woff) {
    __shared__ int ssum[256];
    int b = blockIdx.x, t = threadIdx.x;
    int base = b * 1024 + t * 4;
    int v[4]; int s = 0;
    #pragma unroll
    for (int i = 0; i < 4; ++i) {
        int g = base + i;
        v[i] = (g < NN) ? deg[g] : 0;
        s += v[i];
    }
    ssum[t] = s; __syncthreads();
    for (int off = 1; off < 256; off <<= 1) {
        int val = (t >= off) ? ssum[t - off] : 0;
        __syncthreads();
        ssum[t] += val;
        __syncthreads();
    }
    int excl = (t == 0) ? 0 : ssum[t - 1];
    excl += partial[b];
    #pragma unroll
    for (int i = 0; i < 4; ++i) {
        int g = base + i;
        if (g < NN) { roff[g] = excl; woff[g] = excl; }
        excl += v[i];
    }
    if (b == NB - 1 && t == 255) roff[NN] = EE;
}

// deterministic per-bin prefix over chunks: omat[c][b] = global write base
// for chunk c's bin-b run. 1 block, 128 threads, no atomics.
__global__ void bin_offsets(const int* __restrict__ cmat, const int* __restrict__ roff,
                            int* __restrict__ omat) {
    int b = threadIdx.x;
    if (b >= NBIN) return;
    int d0 = b * BINW;
    int run = roff[d0 < NN ? d0 : NN];
    for (int c = 0; c < NCHUNK; ++c) {
        omat[c * NBIN + b] = run;
        run += cmat[c * NBIN + b];
    }
}

// per chunk: LDS bin-sort, then write each bin's run contiguously at its
// precomputed offset. All global writes are coalesced runs; zero
// contended atomics.
__global__ __launch_bounds__(256) void bin_scatter(
        const int* __restrict__ ei, const int* __restrict__ omat,
        int2* __restrict__ pairs) {
    __shared__ int cnt[NBIN], excl[NBIN], cur[NBIN], gbase[NBIN];
    __shared__ int2 stg[CH];
    __shared__ unsigned char binof[CH];
    const int t = threadIdx.x;
    const int c = blockIdx.x;
    const int c0 = c * CH;
    const int nc = min(CH, EE - c0);
    if (t < NBIN) cnt[t] = 0;
    __syncthreads();
    int msrc[8], mdst[8], mbin[8];
    #pragma unroll
    for (int i = 0; i < 8; ++i) {
        int idx = t + i * 256;
        if (idx < nc) {
            msrc[i] = ei[c0 + idx];
            mdst[i] = ei[EE + c0 + idx];
            mbin[i] = mdst[i] / BINW;
            atomicAdd(&cnt[mbin[i]], 1);
        }
    }
    __syncthreads();
    if (t < NBIN) excl[t] = cnt[t];
    __syncthreads();
    for (int off = 1; off < NBIN; off <<= 1) {
        int v = (t < NBIN && t >= off) ? excl[t - off] : 0;
        __syncthreads();
        if (t < NBIN) excl[t] += v;
        __syncthreads();
    }
    if (t < NBIN) {
        int e2 = excl[t] - cnt[t];
        excl[t] = e2; cur[t] = e2;
        gbase[t] = omat[c * NBIN + t];
    }
    __syncthreads();
    #pragma unroll
    for (int i = 0; i < 8; ++i) {
        int idx = t + i * 256;
        if (idx < nc) {
            int pos = atomicAdd(&cur[mbin[i]], 1);
            stg[pos] = make_int2(msrc[i], mdst[i]);
            binof[pos] = (unsigned char)mbin[i];
        }
    }
    __syncthreads();
    for (int i = t; i < nc; i += 256) {
        int b = binof[i];
        pairs[gbase[b] + (i - excl[b])] = stg[i];
    }
}

// one block per bin: LDS counting sort by dst (cursors from roff), stream
// esrc out contiguously. Block-private window -> no cross-XCD ping-pong.
__global__ __launch_bounds__(256) void bin_sort(
        const int2* __restrict__ pairs, const int* __restrict__ roff,
        int* __restrict__ esrc) {
    __shared__ int cursor[BINW];     // 3.1 KB
    __shared__ int loc[8192];        // 32 KB (bin mean 6250, +24 sigma safe)
    const int b = blockIdx.x;
    const int t = threadIdx.x;
    const int d0 = b * BINW;
    const int d1 = (d0 + BINW < NN) ? d0 + BINW : NN;
    const int base = roff[d0];
    const int end  = roff[d1];
    const int cnt = end - base;
    for (int d = t; d < d1 - d0; d += 256) cursor[d] = roff[d0 + d] - base;
    __syncthreads();
    for (int i = t; i < cnt; i += 256) {
        int2 p = pairs[base + i];
        int pos = atomicAdd(&cursor[p.y - d0], 1);
        loc[pos] = p.x;
    }
    __syncthreads();
    for (int i = t; i < cnt; i += 256) esrc[base + i] = loc[i];
}

// ---------------- split-precision MFMA GEMM, X staged once in LDS --------
// R15: one block = 128 rows x ALL 26 col-tiles. X (hi+lo) loaded from
// global exactly ONCE per block into XOR-swizzled LDS. Each wave owns 32
// rows and loops over ALL 7 groups.
template <int NCH>
__global__ __launch_bounds__(256, 2) void gemm_mfma(
        const unsigned short* __restrict__ Xh, const unsigned short* __restrict__ Xl,
        const unsigned short* __restrict__ Wfh, const unsigned short* __restrict__ Wfl,
        const float* __restrict__ bp, unsigned short* __restrict__ qbh,
        float* __restrict__ sb, unsigned short* __restrict__ kvb) {
    constexpr int K = NCH * 32;
    constexpr int ROWB = 2 * K;              // bytes per X row (bf16)
    constexpr int SWZ = (NCH == 4) ? 7 : 3;  // row-XOR mask (<<4)
    __shared__ char xlds[2 * 128 * ROWB];    // hi plane then lo plane
    __shared__ char olds[4][32][128];        // per-wave out staging
    const int tid = threadIdx.x;
    const int lane = tid & 63;
    const int wv = tid >> 6;
    const int m0b = blockIdx.x << 7;         // block's 128-row base
    const int ml = lane & 15;
    const int quad = lane >> 4;

    // ---- stage X hi+lo into LDS (coalesced 16B pieces, XOR-swizzled) ----
    {
        const int NP = 128 * ROWB / 16;      // pieces per plane
        const char* gsrc[2] = { (const char*)Xh, (const char*)Xl };
        #pragma unroll
        for (int pl = 0; pl < 2; ++pl) {
            char* dstp = xlds + (size_t)pl * 128 * ROWB;
            for (int p = tid; p < NP; p += 256) {
                int gb = p * 16;
                int row = gb / ROWB;
                int col = gb & (ROWB - 1);
                int grow = m0b + row;
                if (grow >= NN) grow = NN - 1;
                uint4 d = *(const uint4*)(gsrc[pl] + (size_t)grow * ROWB + col);
                *(uint4*)(dstp + row * ROWB + (col ^ ((row & SWZ) << 4))) = d;
            }
        }
    }
    __syncthreads();

    const int m0 = m0b + (wv << 5);          // this wave's 32-row base
    const int rowL0 = (wv << 5) + ml;        // local row, half 0
    const int rowL1 = rowL0 + 16;            // local row, half 1
    char* myl = &olds[wv][0][0];

    // each wave: its 32 rows x ALL 7 column groups
    for (int g = 0; g < 7; ++g) {
        int tiles[4]; int ntl = 4; int gtype;     // 0=q, 1=kv, 2=skip
        if (g < 2) {
            gtype = 0;
            #pragma unroll
            for (int i = 0; i < 4; ++i) tiles[i] = 4 * g + i;
        } else if (g < 6) {
            gtype = 1;
            int j = g - 2;
            tiles[0] = 8 + 2 * j; tiles[1] = 9 + 2 * j;
            tiles[2] = 16 + 2 * j; tiles[3] = 17 + 2 * j;
        } else {
            gtype = 2; ntl = 2;
            tiles[0] = 24; tiles[1] = 25; tiles[2] = 24; tiles[3] = 25;
        }

        floatx4 acc[2][4] = {};

        #pragma unroll
        for (int c = 0; c < NCH; ++c) {
            int colb = (c * 64 + quad * 16);
            int a0 = rowL0 * ROWB + (colb ^ ((rowL0 & SWZ) << 4));
            int a1 = rowL1 * ROWB + (colb ^ ((rowL1 & SWZ) << 4));
            short8 x0h = *(const short8*)(xlds + a0);
            short8 x1h = *(const short8*)(xlds + a1);
            short8 x0l = *(const short8*)(xlds + 128 * ROWB + a0);
            short8 x1l = *(const short8*)(xlds + 128 * ROWB + a1);
            #pragma unroll
            for (int t = 0; t < 4; ++t) {
                if (t < ntl) {
                    size_t boff = (((size_t)c * NTILE + tiles[t]) * 64 + lane) * 8;
                    short8 wh = *(const short8*)(Wfh + boff);
                    short8 wl = *(const short8*)(Wfl + boff);
                    acc[0][t] = __builtin_amdgcn_mfma_f32_16x16x32_bf16(wh, x0h, acc[0][t], 0, 0, 0);
                    acc[0][t] = __builtin_amdgcn_mfma_f32_16x16x32_bf16(wl, x0h, acc[0][t], 0, 0, 0);
                    acc[0][t] = __builtin_amdgcn_mfma_f32_16x16x32_bf16(wh, x0l, acc[0][t], 0, 0, 0);
                    acc[1][t] = __builtin_amdgcn_mfma_f32_16x16x32_bf16(wh, x1h, acc[1][t], 0, 0, 0);
                    acc[1][t] = __builtin_amdgcn_mfma_f32_16x16x32_bf16(wl, x1h, acc[1][t], 0, 0, 0);
                    acc[1][t] = __builtin_amdgcn_mfma_f32_16x16x32_bf16(wh, x1l, acc[1][t], 0, 0, 0);
                }
            }
        }

        // ---- stage into wave-private LDS in FINAL byte order (XOR pitch-128) ----
        #pragma unroll
        for (int t = 0; t < 4; ++t) {
            if (t >= ntl) break;
            int tg = tiles[t];
            int c0 = (tg << 4) + (quad << 2);
            float4 b4 = *(const float4*)(bp + c0);
            #pragma unroll
            for (int mt = 0; mt < 2; ++mt) {
                int row = mt * 16 + ml;
                int sz = (row & 7) << 4;
                float v0 = acc[mt][t][0] + b4.x;
                float v1 = acc[mt][t][1] + b4.y;
                float v2 = acc[mt][t][2] + b4.z;
                float v3 = acc[mt][t][3] + b4.w;
                if (gtype == 2) {                  // skip fp32
                    *(float4*)(myl + row * 128 + ((64 * t + 16 * quad) ^ sz)) =
                        make_float4(v0, v1, v2, v3);
                } else {
                    ushort4 u = {f2bf(v0), f2bf(v1), f2bf(v2), f2bf(v3)};
                    int off;
                    if (gtype == 0) off = 32 * t + 8 * quad;                 // q linear
                    else off = 64 * (t & 1) + 16 * quad + 8 * (t >> 1);      // kv interleave
                    *(ushort4*)(myl + row * 128 + (off ^ sz)) = u;
                }
            }
        }
        // wave-private RAW/WAR: DS pipe is in-order per wave; compiler
        // inserts lgkmcnt waits. No barrier needed.

        // ---- linear read-back + full-line global stores ----
        const int lr = lane >> 3;          // 0..7 row within page
        const int lc = (lane & 7) * 16;    // byte offset in 128-B chunk
        #pragma unroll
        for (int i = 0; i < 4; ++i) {
            int row = i * 8 + lr;
            uint4 d = *(const uint4*)(myl + row * 128 + (lc ^ (lr << 4)));
            int node = m0 + row;
            if (node < NN) {
                char* dst;
                if (gtype == 0)      dst = (char*)qbh + (size_t)node * 256 + g * 128 + lc;
                else if (gtype == 1) dst = (char*)kvb + (size_t)node * 512 + (g - 2) * 128 + lc;
                else                 dst = (char*)sb + (size_t)node * 128 + lc;
                *(uint4*)dst = d;
            }
        }
    }
}

// ---------------- fused attention: ONE NODE PER HALF-WAVE ----------------
// R16 structure (best so far): wave = 2 nodes, 8 independent gathers in
// flight per wave. NO-MAX softmax (logits bounded, fp32 exact).
#define ATTN_STEP(u) {                                                       \
    float k0 = bf_lo((u).x), k1 = bf_hi((u).x);                              \
    float k2 = bf_lo((u).y), k3 = bf_hi((u).y);                              \
    float v0 = bf_lo((u).z), v1 = bf_hi((u).z);                              \
    float v2 = bf_lo((u).w), v3 = bf_hi((u).w);                              \
    float part = q4.x * k0 + q4.y * k1 + q4.z * k2 + q4.w * k3;              \
    part += __shfl_xor(part, 1);                                             \
    part += __shfl_xor(part, 2);                                             \
    part += __shfl_xor(part, 4);                                             \
    float p = exp2f(part);                                                   \
    s += p;                                                                  \
    acc.x += p * v0;                                                         \
    acc.y += p * v1;                                                         \
    acc.z += p * v2;                                                         \
    acc.w += p * v3; }

__global__ __launch_bounds__(256) void fused_attn(
        const unsigned short* __restrict__ qbh, const float* __restrict__ sb,
        const unsigned short* __restrict__ kvb,
        const int* __restrict__ roff, const int* __restrict__ esrc,
        float* __restrict__ hout,
        unsigned short* __restrict__ hh, unsigned short* __restrict__ hl) {
    const int lane = threadIdx.x & 63;
    const int w = (blockIdx.x * blockDim.x + threadIdx.x) >> 6;   // wave id
    const int hw = lane >> 5;
    const int n = 2 * w + hw;          // this half-wave's node
    if (n >= NN) return;               // NN even: whole halves retire
    const int kl = lane & 31;

    ushort4 qu = *(const ushort4*)(qbh + (size_t)n * QBH_W + 4 * kl);
    float4 q4 = make_float4(bf2f(qu.x) * QSCALE, bf2f(qu.y) * QSCALE,
                            bf2f(qu.z) * QSCALE, bf2f(qu.w) * QSCALE);
    // hoist skip row (redundant 4x read, coalesced, overlaps gather loop)
    float4 sk = *(const float4*)(sb + (size_t)n * SB_W + 4 * (kl & 7));

    float s = 0.f;
    float4 acc = make_float4(0.f, 0.f, 0.f, 0.f);
    const int e0 = roff[n];
    const int cnt = roff[n + 1] - e0;
    int i = 0;
    for (; i + 4 <= cnt; i += 4) {
        int b0 = esrc[e0 + i];
        int b1 = esrc[e0 + i + 1];
        int b2 = esrc[e0 + i + 2];
        int b3 = esrc[e0 + i + 3];
        uint4 u0 = *(const uint4*)(kvb + (size_t)b0 * KV_W + 8 * kl);
        uint4 u1 = *(const uint4*)(kvb + (size_t)b1 * KV_W + 8 * kl);
        uint4 u2 = *(const uint4*)(kvb + (size_t)b2 * KV_W + 8 * kl);
        uint4 u3 = *(const uint4*)(kvb + (size_t)b3 * KV_W + 8 * kl);
        ATTN_STEP(u0); ATTN_STEP(u1); ATTN_STEP(u2); ATTN_STEP(u3);
    }
    for (; i < cnt; ++i) {
        int b0 = esrc[e0 + i];
        uint4 u0 = *(const uint4*)(kvb + (size_t)b0 * KV_W + 8 * kl);
        ATTN_STEP(u0);
    }

    float inv = (s > 0.f) ? 1.f / s : 0.f;
    float4 o;
    o.x = acc.x * inv; o.y = acc.y * inv; o.z = acc.z * inv; o.w = acc.w * inv;
    // sum over heads (head bits of kl are bits 3,4; xor 8/16 stay in-half)
    o.x += __shfl_xor(o.x, 8);  o.y += __shfl_xor(o.y, 8);  o.z += __shfl_xor(o.z, 8);  o.w += __shfl_xor(o.w, 8);
    o.x += __shfl_xor(o.x, 16); o.y += __shfl_xor(o.y, 16); o.z += __shfl_xor(o.z, 16); o.w += __shfl_xor(o.w, 16);
    if (kl < 8) {
        float4 rr;
        rr.x = fmaxf(o.x * 0.25f + sk.x, 0.f);
        rr.y = fmaxf(o.y * 0.25f + sk.y, 0.f);
        rr.z = fmaxf(o.z * 0.25f + sk.z, 0.f);
        rr.w = fmaxf(o.w * 0.25f + sk.w, 0.f);
        int c0 = 4 * kl;
        if (hout)
            *(float4*)(hout + (size_t)n * HID + c0) = rr;
        if (hh) {
            ushort4 uh = {f2bf(rr.x), f2bf(rr.y), f2bf(rr.z), f2bf(rr.w)};
            ushort4 ul = {f2bf(rr.x - bf2f(uh.x)), f2bf(rr.y - bf2f(uh.y)),
                          f2bf(rr.z - bf2f(uh.z)), f2bf(rr.w - bf2f(uh.w))};
            *(ushort4*)(hh + (size_t)n * HID + c0) = uh;
            *(ushort4*)(hl + (size_t)n * HID + c0) = ul;
        }
    }
}

// ---------------- final linear: out = h @ Wout + bout --------------------
__global__ void out_linear(const float* __restrict__ h, const float* __restrict__ Wout,
                           const float* __restrict__ bout, float* __restrict__ out) {
    int idx = blockIdx.x * blockDim.x + threadIdx.x;
    if (idx >= NN * OUT_DIM) return;
    int n = idx >> 4;
    int j = idx & 15;
    float accv = bout[j];
    #pragma unroll
    for (int k = 0; k < HID; ++k)
        accv += h[(size_t)n * HID + k] * Wout[k * OUT_DIM + j];
    out[idx] = accv;
}

extern "C" void kernel_launch(void* const* d_in, const int* in_sizes, int n_in,
                              void* d_out, int out_size, void* d_ws, size_t ws_size,
                              hipStream_t stream) {
    const float* x  = (const float*)d_in[0];
    const int*   ei = (const int*)d_in[1];
    const float* l0w[8]; const float* l1w[8];
    for (int i = 0; i < 8; ++i) { l0w[i] = (const float*)d_in[2 + i]; l1w[i] = (const float*)d_in[10 + i]; }
    const float* Wout = (const float*)d_in[18];
    const float* bout = (const float*)d_in[19];
    float* out = (float*)d_out;

    // workspace layout
    float* ws = (float*)d_ws;
    float* sb   = ws;                           // NN*32 floats
    float* h0   = sb + (size_t)NN * SB_W;       // NN*32
    float* bp0  = h0 + (size_t)NN * HID;        // 416
    float* bp1  = bp0 + COLS;                   // 416
    unsigned short* qbh  = (unsigned short*)(bp1 + COLS);    // NN*128 bf16
    unsigned short* kvb  = qbh + (size_t)NN * QBH_W;         // NN*256 bf16
    unsigned short* xh   = kvb + (size_t)NN * KV_W;          // NN*128
    unsigned short* xl   = xh + (size_t)NN * IN_DIM;         // NN*128
    unsigned short* hh   = xl + (size_t)NN * IN_DIM;         // NN*32
    unsigned short* hl   = hh + (size_t)NN * HID;            // NN*32
    unsigned short* Wf0h = hl + (size_t)NN * HID;            // 4*26*64*8
    unsigned short* Wf0l = Wf0h + 4 * NTILE * 64 * 8;
    unsigned short* Wf1h = Wf0l + 4 * NTILE * 64 * 8;        // 1*26*64*8
    unsigned short* Wf1l = Wf1h + NTILE * 64 * 8;
    int* ibase  = (int*)(Wf1l + NTILE * 64 * 8);
    int* deg     = ibase;                       // NN
    int* roff    = deg + NN;                    // NN+1
    int* woff    = roff + NN + 1;               // NN
    int* partial = woff + NN;                   // NB
    int* esrc    = partial + NB;                // EE
    int* cmat    = esrc + EE;                   // NCHUNK*NBIN (~200KB)
    int* omat    = cmat + NCHUNK * NBIN;        // NCHUNK*NBIN

    // pairs scratch ALIASED onto xh/xl (CSR build runs before to_bf16_split
    // in stream order, so lifetimes don't overlap)
    int2* pairs = (int2*)xh;                    // EE int2 (6.4 MB)

    // pack BOTH layers' weights in one launch
    pack_frag2<<<(5 * NTILE * 64 + 255) / 256, 256, 0, stream>>>(
        l0w[0], l0w[2], l0w[4], l0w[6], l0w[1], l0w[3], l0w[5], l0w[7],
        l1w[0], l1w[2], l1w[4], l1w[6], l1w[1], l1w[3], l1w[5], l1w[7],
        Wf0h, Wf0l, bp0, Wf1h, Wf1l, bp1);

    // ---- CSR build: atomic-free deterministic bin sort ----
    hipMemsetAsync(deg, 0, NN * sizeof(int), stream);
    chunk_hist<<<NCHUNK, 256, 0, stream>>>(ei, deg, cmat);
    block_sum<<<NB, 256, 0, stream>>>(deg, partial);
    scan_partial<<<1, 64, 0, stream>>>(partial);
    block_scan<<<NB, 256, 0, stream>>>(deg, partial, roff, woff);
    bin_offsets<<<1, 128, 0, stream>>>(cmat, roff, omat);
    bin_scatter<<<NCHUNK, 256, 0, stream>>>(ei, omat, pairs);
    bin_sort<<<NBIN, 256, 0, stream>>>(pairs, roff, esrc);

    // now safe to overwrite xh/xl
    to_bf16_split<<<(NN * IN_DIM / 4 + 255) / 256, 256, 0, stream>>>(x, xh, xl, NN * IN_DIM / 4);

    const int gemm_blocks = (NN + 127) / 128;    // 782, one block = 128 rows x all tiles
    const int attn_waves = (NN + 1) / 2;         // one node per half-wave
    const int attn_blocks = (attn_waves * 64 + 255) / 256;   // 12500

    // layer 0 (attn writes only hh/hl)
    gemm_mfma<4><<<gemm_blocks, 256, 0, stream>>>(xh, xl, Wf0h, Wf0l, bp0, qbh, sb, kvb);
    fused_attn<<<attn_blocks, 256, 0, stream>>>(qbh, sb, kvb, roff, esrc, (float*)nullptr, hh, hl);

    // layer 1 (attn writes only h0)
    gemm_mfma<1><<<gemm_blocks, 256, 0, stream>>>(hh, hl, Wf1h, Wf1l, bp1, qbh, sb, kvb);
    fused_attn<<<attn_blocks, 256, 0, stream>>>(qbh, sb, kvb, roff, esrc, h0,
                                                (unsigned short*)nullptr, (unsigned short*)nullptr);

    // output linear
    out_linear<<<(NN * OUT_DIM + 255) / 256, 256, 0, stream>>>(h0, Wout, bout, out);
}

// Round 9
// 436.268 us; speedup vs baseline: 1.7141x; 1.0177x over previous
//
#include <hip/hip_runtime.h>
#include <math.h>

#define NN 100000
#define EE 800000
#define IN_DIM 128
#define HID 32
#define HEADS 4
#define QKV 128         // HEADS*HID
#define COLS 416        // 3*QKV + HID (q|k|v|skip)
#define QBH_W 128       // q bf16 row (256 B)
#define SB_W 32         // skip fp32 row (128 B)
#define KV_W 256        // interleaved bf16: 32 groups of [k x4 | v x4] (512-B rows)
#define OUT_DIM 16
#define NB 98           // ceil(NN/1024) scan blocks
#define NTILE 26        // 416/16 col-tiles
#define NBIN 128        // dst-range bins for CSR sort
#define BINW 782        // ceil(NN/NBIN); 128*782 = 100096 >= NN
#define CH 2048         // edges per chunk
#define NCHUNK 391      // ceil(EE/CH)
// (1/sqrt(32)) * log2(e): pre-folded into q so p = exp2(part)
#define QSCALE 0.25503512f

typedef __attribute__((ext_vector_type(8))) short short8;
typedef __attribute__((ext_vector_type(4))) float floatx4;

__device__ __forceinline__ unsigned short f2bf(float f) {
    unsigned int u = __float_as_uint(f);
    unsigned int r = (u + 0x7FFF + ((u >> 16) & 1)) >> 16;   // RNE
    return (unsigned short)r;
}
__device__ __forceinline__ float bf2f(unsigned short h) {
    return __uint_as_float((unsigned int)h << 16);
}
__device__ __forceinline__ float bf_lo(unsigned int d) {
    return __uint_as_float(d << 16);
}
__device__ __forceinline__ float bf_hi(unsigned int d) {
    return __uint_as_float(d & 0xFFFF0000u);
}

// ---------------- fragment-pack BOTH layers' W (split hi/lo) + biases ----
// Wf[((c*26 + t)*64 + lane)*8 + j] = W[(c*32 + (lane>>4)*8 + j)][t*16 + (lane&15)]
__device__ __forceinline__ void pack_one(
        const float* __restrict__ Wq, const float* __restrict__ Wk,
        const float* __restrict__ Wv, const float* __restrict__ Ws,
        const float* __restrict__ bq, const float* __restrict__ bk,
        const float* __restrict__ bv, const float* __restrict__ bs,
        unsigned short* __restrict__ Wfh, unsigned short* __restrict__ Wfl,
        float* __restrict__ bp, int K, int idx) {
    if (idx < COLS) {
        float b;
        if (idx < 128)      b = bq[idx];
        else if (idx < 256) b = bk[idx - 128];
        else if (idx < 384) b = bv[idx - 256];
        else                b = bs[idx - 384];
        bp[idx] = b;
    }
    int nch = K >> 5;
    if (idx >= nch * NTILE * 64) return;
    int lane = idx & 63;
    int tt = (idx >> 6) % NTILE;
    int c = idx / (NTILE * 64);
    int k0 = c * 32 + (lane >> 4) * 8;
    int col = tt * 16 + (lane & 15);
    #pragma unroll
    for (int j = 0; j < 8; ++j) {
        int k = k0 + j;
        float w;
        if (col < 128)      w = Wq[(size_t)k * 128 + col];
        else if (col < 256) w = Wk[(size_t)k * 128 + (col - 128)];
        else if (col < 384) w = Wv[(size_t)k * 128 + (col - 256)];
        else                w = Ws[(size_t)k * 32 + (col - 384)];
        unsigned short hi = f2bf(w);
        float rem = w - bf2f(hi);
        Wfh[(size_t)idx * 8 + j] = hi;
        Wfl[(size_t)idx * 8 + j] = f2bf(rem);
    }
}

__global__ void pack_frag2(
        const float* __restrict__ Wq0, const float* __restrict__ Wk0,
        const float* __restrict__ Wv0, const float* __restrict__ Ws0,
        const float* __restrict__ bq0, const float* __restrict__ bk0,
        const float* __restrict__ bv0, const float* __restrict__ bs0,
        const float* __restrict__ Wq1, const float* __restrict__ Wk1,
        const float* __restrict__ Wv1, const float* __restrict__ Ws1,
        const float* __restrict__ bq1, const float* __restrict__ bk1,
        const float* __restrict__ bv1, const float* __restrict__ bs1,
        unsigned short* __restrict__ Wf0h, unsigned short* __restrict__ Wf0l,
        float* __restrict__ bp0,
        unsigned short* __restrict__ Wf1h, unsigned short* __restrict__ Wf1l,
        float* __restrict__ bp1) {
    const int L0N = 4 * NTILE * 64;   // 6656
    int gid = blockIdx.x * blockDim.x + threadIdx.x;
    if (gid < L0N) {
        pack_one(Wq0, Wk0, Wv0, Ws0, bq0, bk0, bv0, bs0, Wf0h, Wf0l, bp0, 128, gid);
    } else {
        pack_one(Wq1, Wk1, Wv1, Ws1, bq1, bk1, bv1, bs1, Wf1h, Wf1l, bp1, 32, gid - L0N);
    }
}

// ---------------- CSR build: ATOMIC-FREE deterministic bin sort ----------
// R19 lesson (R17/R18 measured): per-element contended global atomics
// serialize (~12ns/op per cache line) and random small writes amplify
// 6-16x across non-coherent XCD L2s. This pipeline histograms in LDS,
// derives all global offsets deterministically, and makes every global
// write a coalesced run.

// one block per 2048-edge chunk: LDS 128-bin hist -> cmat row, plus
// per-dst degree (random atomics over 400KB -> low contention, cheap).
__global__ __launch_bounds__(256) void chunk_hist(
        const int* __restrict__ ei, int* __restrict__ deg,
        int* __restrict__ cmat) {
    __shared__ int cnt[NBIN];
    const int t = threadIdx.x;
    const int c = blockIdx.x;
    const int c0 = c * CH;
    const int nc = min(CH, EE - c0);
    if (t < NBIN) cnt[t] = 0;
    __syncthreads();
    for (int i = t; i < nc; i += 256) {
        int d = ei[EE + c0 + i];
        atomicAdd(&deg[d], 1);
        atomicAdd(&cnt[d / BINW], 1);
    }
    __syncthreads();
    if (t < NBIN) cmat[c * NBIN + t] = cnt[t];
}

__global__ void block_sum(const int* __restrict__ deg, int* __restrict__ partial) {
    __shared__ int sdata[256];
    int b = blockIdx.x, t = threadIdx.x;
    int sum = 0;
    for (int i = t; i < 1024; i += 256) {
        int g = b * 1024 + i;
        if (g < NN) sum += deg[g];
    }
    sdata[t] = sum; __syncthreads();
    for (int s = 128; s > 0; s >>= 1) {
        if (t < s) sdata[t] += sdata[t + s];
        __syncthreads();
    }
    if (t == 0) partial[b] = sdata[0];
}

// wave-parallel exclusive scan of the NB partials (NB <= 128)
__global__ void scan_partial(int* __restrict__ partial) {
    int l = threadIdx.x;   // 64 threads
    int a = (l < NB) ? partial[l] : 0;
    int b = (l + 64 < NB) ? partial[l + 64] : 0;
    for (int off = 1; off < 64; off <<= 1) {
        int v = __shfl_up(a, off);
        if (l >= off) a += v;
    }
    int tot = __shfl(a, 63);
    for (int off = 1; off < 64; off <<= 1) {
        int v = __shfl_up(b, off);
        if (l >= off) b += v;
    }
    b += tot;
    int ea = __shfl_up(a, 1); if (l == 0) ea = 0;
    int eb = __shfl_up(b, 1); if (l == 0) eb = tot;
    if (l < NB) partial[l] = ea;
    if (l + 64 < NB) partial[l + 64] = eb;
}

__global__ void block_scan(const int* __restrict__ deg, const int* __restrict__ partial,
                           int* __restrict__ roff, int* __restrict__ woff) {
    __shared__ int ssum[256];
    int b = blockIdx.x, t = threadIdx.x;
    int base = b * 1024 + t * 4;
    int v[4]; int s = 0;
    #pragma unroll
    for (int i = 0; i < 4; ++i) {
        int g = base + i;
        v[i] = (g < NN) ? deg[g] : 0;
        s += v[i];
    }
    ssum[t] = s; __syncthreads();
    for (int off = 1; off < 256; off <<= 1) {
        int val = (t >= off) ? ssum[t - off] : 0;
        __syncthreads();
        ssum[t] += val;
        __syncthreads();
    }
    int excl = (t == 0) ? 0 : ssum[t - 1];
    excl += partial[b];
    #pragma unroll
    for (int i = 0; i < 4; ++i) {
        int g = base + i;
        if (g < NN) { roff[g] = excl; woff[g] = excl; }
        excl += v[i];
    }
    if (b == NB - 1 && t == 255) roff[NN] = EE;
}

// deterministic per-bin prefix over chunks: omat[c][b] = global write base
// for chunk c's bin-b run. 1 block, 128 threads, no atomics.
__global__ void bin_offsets(const int* __restrict__ cmat, const int* __restrict__ roff,
                            int* __restrict__ omat) {
    int b = threadIdx.x;
    if (b >= NBIN) return;
    int d0 = b * BINW;
    int run = roff[d0 < NN ? d0 : NN];
    for (int c = 0; c < NCHUNK; ++c) {
        omat[c * NBIN + b] = run;
        run += cmat[c * NBIN + b];
    }
}

// per chunk: LDS bin-sort, then write each bin's run contiguously at its
// precomputed offset. All global writes are coalesced runs; zero
// contended atomics.
__global__ __launch_bounds__(256) void bin_scatter(
        const int* __restrict__ ei, const int* __restrict__ omat,
        int2* __restrict__ pairs) {
    __shared__ int cnt[NBIN], excl[NBIN], cur[NBIN], gbase[NBIN];
    __shared__ int2 stg[CH];
    __shared__ unsigned char binof[CH];
    const int t = threadIdx.x;
    const int c = blockIdx.x;
    const int c0 = c * CH;
    const int nc = min(CH, EE - c0);
    if (t < NBIN) cnt[t] = 0;
    __syncthreads();
    int msrc[8], mdst[8], mbin[8];
    #pragma unroll
    for (int i = 0; i < 8; ++i) {
        int idx = t + i * 256;
        if (idx < nc) {
            msrc[i] = ei[c0 + idx];
            mdst[i] = ei[EE + c0 + idx];
            mbin[i] = mdst[i] / BINW;
            atomicAdd(&cnt[mbin[i]], 1);
        }
    }
    __syncthreads();
    if (t < NBIN) excl[t] = cnt[t];
    __syncthreads();
    for (int off = 1; off < NBIN; off <<= 1) {
        int v = (t < NBIN && t >= off) ? excl[t - off] : 0;
        __syncthreads();
        if (t < NBIN) excl[t] += v;
        __syncthreads();
    }
    if (t < NBIN) {
        int e2 = excl[t] - cnt[t];
        excl[t] = e2; cur[t] = e2;
        gbase[t] = omat[c * NBIN + t];
    }
    __syncthreads();
    #pragma unroll
    for (int i = 0; i < 8; ++i) {
        int idx = t + i * 256;
        if (idx < nc) {
            int pos = atomicAdd(&cur[mbin[i]], 1);
            stg[pos] = make_int2(msrc[i], mdst[i]);
            binof[pos] = (unsigned char)mbin[i];
        }
    }
    __syncthreads();
    for (int i = t; i < nc; i += 256) {
        int b = binof[i];
        pairs[gbase[b] + (i - excl[b])] = stg[i];
    }
}

// one block per bin: LDS counting sort by dst (cursors from roff), stream
// esrc out contiguously. Block-private window -> no cross-XCD ping-pong.
__global__ __launch_bounds__(256) void bin_sort(
        const int2* __restrict__ pairs, const int* __restrict__ roff,
        int* __restrict__ esrc) {
    __shared__ int cursor[BINW];     // 3.1 KB
    __shared__ int loc[8192];        // 32 KB (bin mean 6250, +24 sigma safe)
    const int b = blockIdx.x;
    const int t = threadIdx.x;
    const int d0 = b * BINW;
    const int d1 = (d0 + BINW < NN) ? d0 + BINW : NN;
    const int base = roff[d0];
    const int end  = roff[d1];
    const int cnt = end - base;
    for (int d = t; d < d1 - d0; d += 256) cursor[d] = roff[d0 + d] - base;
    __syncthreads();
    for (int i = t; i < cnt; i += 256) {
        int2 p = pairs[base + i];
        int pos = atomicAdd(&cursor[p.y - d0], 1);
        loc[pos] = p.x;
    }
    __syncthreads();
    for (int i = t; i < cnt; i += 256) esrc[base + i] = loc[i];
}

// ---------------- split-precision MFMA GEMM, X staged once in LDS --------
// R20: template<NCH, F32>. F32 path (layer 0) reads X fp32 directly and
// does the hi/lo bf16 split DURING LDS staging -> the separate
// to_bf16_split pass (51 MB read + 51 MB write + 51 MB re-read) is gone.
// 8-B plane writes preserve the 16-B XOR-swizzle (XOR bits 4-6 don't
// touch bit 3); 2-way LDS bank aliasing is free (m136).
template <int NCH, bool F32>
__global__ __launch_bounds__(256, 2) void gemm_mfma(
        const void* __restrict__ A0, const void* __restrict__ A1,
        const unsigned short* __restrict__ Wfh, const unsigned short* __restrict__ Wfl,
        const float* __restrict__ bp, unsigned short* __restrict__ qbh,
        float* __restrict__ sb, unsigned short* __restrict__ kvb) {
    constexpr int K = NCH * 32;
    constexpr int ROWB = 2 * K;              // bytes per X row (bf16)
    constexpr int SWZ = (NCH == 4) ? 7 : 3;  // row-XOR mask (<<4)
    __shared__ char xlds[2 * 128 * ROWB];    // hi plane then lo plane
    __shared__ char olds[4][32][128];        // per-wave out staging
    const int tid = threadIdx.x;
    const int lane = tid & 63;
    const int wv = tid >> 6;
    const int m0b = blockIdx.x << 7;         // block's 128-row base
    const int ml = lane & 15;
    const int quad = lane >> 4;

    // ---- stage X hi+lo into LDS (coalesced, XOR-swizzled) ----
    if constexpr (F32) {
        const char* X = (const char*)A0;     // fp32, row = 4*K bytes
        const int NPF = 128 * (K / 4);       // 16-B fp32 pieces
        for (int p = tid; p < NPF; p += 256) {
            int row = p / (K / 4);
            int pc = p % (K / 4);            // 16-B piece within row
            int grow = m0b + row;
            if (grow >= NN) grow = NN - 1;
            float4 v = *(const float4*)(X + (size_t)grow * (4 * K) + pc * 16);
            ushort4 h = {f2bf(v.x), f2bf(v.y), f2bf(v.z), f2bf(v.w)};
            ushort4 l = {f2bf(v.x - bf2f(h.x)), f2bf(v.y - bf2f(h.y)),
                         f2bf(v.z - bf2f(h.z)), f2bf(v.w - bf2f(h.w))};
            int addr = row * ROWB + ((pc * 8) ^ ((row & SWZ) << 4));
            *(ushort4*)(xlds + addr) = h;
            *(ushort4*)(xlds + 128 * ROWB + addr) = l;
        }
    } else {
        const int NP = 128 * ROWB / 16;      // pieces per plane
        const char* gsrc[2] = { (const char*)A0, (const char*)A1 };
        #pragma unroll
        for (int pl = 0; pl < 2; ++pl) {
            char* dstp = xlds + (size_t)pl * 128 * ROWB;
            for (int p = tid; p < NP; p += 256) {
                int gb = p * 16;
                int row = gb / ROWB;
                int col = gb & (ROWB - 1);
                int grow = m0b + row;
                if (grow >= NN) grow = NN - 1;
                uint4 d = *(const uint4*)(gsrc[pl] + (size_t)grow * ROWB + col);
                *(uint4*)(dstp + row * ROWB + (col ^ ((row & SWZ) << 4))) = d;
            }
        }
    }
    __syncthreads();

    const int m0 = m0b + (wv << 5);          // this wave's 32-row base
    const int rowL0 = (wv << 5) + ml;        // local row, half 0
    const int rowL1 = rowL0 + 16;            // local row, half 1
    char* myl = &olds[wv][0][0];

    // each wave: its 32 rows x ALL 7 column groups
    for (int g = 0; g < 7; ++g) {
        int tiles[4]; int ntl = 4; int gtype;     // 0=q, 1=kv, 2=skip
        if (g < 2) {
            gtype = 0;
            #pragma unroll
            for (int i = 0; i < 4; ++i) tiles[i] = 4 * g + i;
        } else if (g < 6) {
            gtype = 1;
            int j = g - 2;
            tiles[0] = 8 + 2 * j; tiles[1] = 9 + 2 * j;
            tiles[2] = 16 + 2 * j; tiles[3] = 17 + 2 * j;
        } else {
            gtype = 2; ntl = 2;
            tiles[0] = 24; tiles[1] = 25; tiles[2] = 24; tiles[3] = 25;
        }

        floatx4 acc[2][4] = {};

        #pragma unroll
        for (int c = 0; c < NCH; ++c) {
            int colb = (c * 64 + quad * 16);
            int a0 = rowL0 * ROWB + (colb ^ ((rowL0 & SWZ) << 4));
            int a1 = rowL1 * ROWB + (colb ^ ((rowL1 & SWZ) << 4));
            short8 x0h = *(const short8*)(xlds + a0);
            short8 x1h = *(const short8*)(xlds + a1);
            short8 x0l = *(const short8*)(xlds + 128 * ROWB + a0);
            short8 x1l = *(const short8*)(xlds + 128 * ROWB + a1);
            #pragma unroll
            for (int t = 0; t < 4; ++t) {
                if (t < ntl) {
                    size_t boff = (((size_t)c * NTILE + tiles[t]) * 64 + lane) * 8;
                    short8 wh = *(const short8*)(Wfh + boff);
                    short8 wl = *(const short8*)(Wfl + boff);
                    acc[0][t] = __builtin_amdgcn_mfma_f32_16x16x32_bf16(wh, x0h, acc[0][t], 0, 0, 0);
                    acc[0][t] = __builtin_amdgcn_mfma_f32_16x16x32_bf16(wl, x0h, acc[0][t], 0, 0, 0);
                    acc[0][t] = __builtin_amdgcn_mfma_f32_16x16x32_bf16(wh, x0l, acc[0][t], 0, 0, 0);
                    acc[1][t] = __builtin_amdgcn_mfma_f32_16x16x32_bf16(wh, x1h, acc[1][t], 0, 0, 0);
                    acc[1][t] = __builtin_amdgcn_mfma_f32_16x16x32_bf16(wl, x1h, acc[1][t], 0, 0, 0);
                    acc[1][t] = __builtin_amdgcn_mfma_f32_16x16x32_bf16(wh, x1l, acc[1][t], 0, 0, 0);
                }
            }
        }

        // ---- stage into wave-private LDS in FINAL byte order (XOR pitch-128) ----
        #pragma unroll
        for (int t = 0; t < 4; ++t) {
            if (t >= ntl) break;
            int tg = tiles[t];
            int c0 = (tg << 4) + (quad << 2);
            float4 b4 = *(const float4*)(bp + c0);
            #pragma unroll
            for (int mt = 0; mt < 2; ++mt) {
                int row = mt * 16 + ml;
                int sz = (row & 7) << 4;
                float v0 = acc[mt][t][0] + b4.x;
                float v1 = acc[mt][t][1] + b4.y;
                float v2 = acc[mt][t][2] + b4.z;
                float v3 = acc[mt][t][3] + b4.w;
                if (gtype == 2) {                  // skip fp32
                    *(float4*)(myl + row * 128 + ((64 * t + 16 * quad) ^ sz)) =
                        make_float4(v0, v1, v2, v3);
                } else {
                    ushort4 u = {f2bf(v0), f2bf(v1), f2bf(v2), f2bf(v3)};
                    int off;
                    if (gtype == 0) off = 32 * t + 8 * quad;                 // q linear
                    else off = 64 * (t & 1) + 16 * quad + 8 * (t >> 1);      // kv interleave
                    *(ushort4*)(myl + row * 128 + (off ^ sz)) = u;
                }
            }
        }
        // wave-private RAW/WAR: DS pipe is in-order per wave; compiler
        // inserts lgkmcnt waits. No barrier needed.

        // ---- linear read-back + full-line global stores ----
        const int lr = lane >> 3;          // 0..7 row within page
        const int lc = (lane & 7) * 16;    // byte offset in 128-B chunk
        #pragma unroll
        for (int i = 0; i < 4; ++i) {
            int row = i * 8 + lr;
            uint4 d = *(const uint4*)(myl + row * 128 + (lc ^ (lr << 4)));
            int node = m0 + row;
            if (node < NN) {
                char* dst;
                if (gtype == 0)      dst = (char*)qbh + (size_t)node * 256 + g * 128 + lc;
                else if (gtype == 1) dst = (char*)kvb + (size_t)node * 512 + (g - 2) * 128 + lc;
                else                 dst = (char*)sb + (size_t)node * 128 + lc;
                *(uint4*)dst = d;
            }
        }
    }
}

// ---------------- fused attention: ONE NODE PER HALF-WAVE ----------------
// R16 structure (best so far): wave = 2 nodes, 8 independent gathers in
// flight per wave. NO-MAX softmax (logits bounded, fp32 exact).
#define ATTN_STEP(u) {                                                       \
    float k0 = bf_lo((u).x), k1 = bf_hi((u).x);                              \
    float k2 = bf_lo((u).y), k3 = bf_hi((u).y);                              \
    float v0 = bf_lo((u).z), v1 = bf_hi((u).z);                              \
    float v2 = bf_lo((u).w), v3 = bf_hi((u).w);                              \
    float part = q4.x * k0 + q4.y * k1 + q4.z * k2 + q4.w * k3;              \
    part += __shfl_xor(part, 1);                                             \
    part += __shfl_xor(part, 2);                                             \
    part += __shfl_xor(part, 4);                                             \
    float p = exp2f(part);                                                   \
    s += p;                                                                  \
    acc.x += p * v0;                                                         \
    acc.y += p * v1;                                                         \
    acc.z += p * v2;                                                         \
    acc.w += p * v3; }

__global__ __launch_bounds__(256) void fused_attn(
        const unsigned short* __restrict__ qbh, const float* __restrict__ sb,
        const unsigned short* __restrict__ kvb,
        const int* __restrict__ roff, const int* __restrict__ esrc,
        float* __restrict__ hout,
        unsigned short* __restrict__ hh, unsigned short* __restrict__ hl) {
    const int lane = threadIdx.x & 63;
    const int w = (blockIdx.x * blockDim.x + threadIdx.x) >> 6;   // wave id
    const int hw = lane >> 5;
    const int n = 2 * w + hw;          // this half-wave's node
    if (n >= NN) return;               // NN even: whole halves retire
    const int kl = lane & 31;

    ushort4 qu = *(const ushort4*)(qbh + (size_t)n * QBH_W + 4 * kl);
    float4 q4 = make_float4(bf2f(qu.x) * QSCALE, bf2f(qu.y) * QSCALE,
                            bf2f(qu.z) * QSCALE, bf2f(qu.w) * QSCALE);
    // hoist skip row (redundant 4x read, coalesced, overlaps gather loop)
    float4 sk = *(const float4*)(sb + (size_t)n * SB_W + 4 * (kl & 7));

    float s = 0.f;
    float4 acc = make_float4(0.f, 0.f, 0.f, 0.f);
    const int e0 = roff[n];
    const int cnt = roff[n + 1] - e0;
    int i = 0;
    for (; i + 4 <= cnt; i += 4) {
        int b0 = esrc[e0 + i];
        int b1 = esrc[e0 + i + 1];
        int b2 = esrc[e0 + i + 2];
        int b3 = esrc[e0 + i + 3];
        uint4 u0 = *(const uint4*)(kvb + (size_t)b0 * KV_W + 8 * kl);
        uint4 u1 = *(const uint4*)(kvb + (size_t)b1 * KV_W + 8 * kl);
        uint4 u2 = *(const uint4*)(kvb + (size_t)b2 * KV_W + 8 * kl);
        uint4 u3 = *(const uint4*)(kvb + (size_t)b3 * KV_W + 8 * kl);
        ATTN_STEP(u0); ATTN_STEP(u1); ATTN_STEP(u2); ATTN_STEP(u3);
    }
    for (; i < cnt; ++i) {
        int b0 = esrc[e0 + i];
        uint4 u0 = *(const uint4*)(kvb + (size_t)b0 * KV_W + 8 * kl);
        ATTN_STEP(u0);
    }

    float inv = (s > 0.f) ? 1.f / s : 0.f;
    float4 o;
    o.x = acc.x * inv; o.y = acc.y * inv; o.z = acc.z * inv; o.w = acc.w * inv;
    // sum over heads (head bits of kl are bits 3,4; xor 8/16 stay in-half)
    o.x += __shfl_xor(o.x, 8);  o.y += __shfl_xor(o.y, 8);  o.z += __shfl_xor(o.z, 8);  o.w += __shfl_xor(o.w, 8);
    o.x += __shfl_xor(o.x, 16); o.y += __shfl_xor(o.y, 16); o.z += __shfl_xor(o.z, 16); o.w += __shfl_xor(o.w, 16);
    if (kl < 8) {
        float4 rr;
        rr.x = fmaxf(o.x * 0.25f + sk.x, 0.f);
        rr.y = fmaxf(o.y * 0.25f + sk.y, 0.f);
        rr.z = fmaxf(o.z * 0.25f + sk.z, 0.f);
        rr.w = fmaxf(o.w * 0.25f + sk.w, 0.f);
        int c0 = 4 * kl;
        if (hout)
            *(float4*)(hout + (size_t)n * HID + c0) = rr;
        if (hh) {
            ushort4 uh = {f2bf(rr.x), f2bf(rr.y), f2bf(rr.z), f2bf(rr.w)};
            ushort4 ul = {f2bf(rr.x - bf2f(uh.x)), f2bf(rr.y - bf2f(uh.y)),
                          f2bf(rr.z - bf2f(uh.z)), f2bf(rr.w - bf2f(uh.w))};
            *(ushort4*)(hh + (size_t)n * HID + c0) = uh;
            *(ushort4*)(hl + (size_t)n * HID + c0) = ul;
        }
    }
}

// ---------------- final linear: out = h @ Wout + bout --------------------
__global__ void out_linear(const float* __restrict__ h, const float* __restrict__ Wout,
                           const float* __restrict__ bout, float* __restrict__ out) {
    int idx = blockIdx.x * blockDim.x + threadIdx.x;
    if (idx >= NN * OUT_DIM) return;
    int n = idx >> 4;
    int j = idx & 15;
    float accv = bout[j];
    #pragma unroll
    for (int k = 0; k < HID; ++k)
        accv += h[(size_t)n * HID + k] * Wout[k * OUT_DIM + j];
    out[idx] = accv;
}

extern "C" void kernel_launch(void* const* d_in, const int* in_sizes, int n_in,
                              void* d_out, int out_size, void* d_ws, size_t ws_size,
                              hipStream_t stream) {
    const float* x  = (const float*)d_in[0];
    const int*   ei = (const int*)d_in[1];
    const float* l0w[8]; const float* l1w[8];
    for (int i = 0; i < 8; ++i) { l0w[i] = (const float*)d_in[2 + i]; l1w[i] = (const float*)d_in[10 + i]; }
    const float* Wout = (const float*)d_in[18];
    const float* bout = (const float*)d_in[19];
    float* out = (float*)d_out;

    // workspace layout
    float* ws = (float*)d_ws;
    float* sb   = ws;                           // NN*32 floats
    float* h0   = sb + (size_t)NN * SB_W;       // NN*32
    float* bp0  = h0 + (size_t)NN * HID;        // 416
    float* bp1  = bp0 + COLS;                   // 416
    unsigned short* qbh  = (unsigned short*)(bp1 + COLS);    // NN*128 bf16
    unsigned short* kvb  = qbh + (size_t)NN * QBH_W;         // NN*256 bf16
    unsigned short* hh   = kvb + (size_t)NN * KV_W;          // NN*32
    unsigned short* hl   = hh + (size_t)NN * HID;            // NN*32
    unsigned short* Wf0h = hl + (size_t)NN * HID;            // 4*26*64*8
    unsigned short* Wf0l = Wf0h + 4 * NTILE * 64 * 8;
    unsigned short* Wf1h = Wf0l + 4 * NTILE * 64 * 8;        // 1*26*64*8
    unsigned short* Wf1l = Wf1h + NTILE * 64 * 8;
    int* ibase  = (int*)(Wf1l + NTILE * 64 * 8);
    int* deg     = ibase;                       // NN
    int* roff    = deg + NN;                    // NN+1
    int* woff    = roff + NN + 1;               // NN
    int* partial = woff + NN;                   // NB
    int* esrc    = partial + NB;                // EE
    int* cmat    = esrc + EE;                   // NCHUNK*NBIN (~200KB)
    int* omat    = cmat + NCHUNK * NBIN;        // NCHUNK*NBIN
    int2* pairs  = (int2*)(omat + NCHUNK * NBIN);  // EE int2 (6.4 MB)

    // pack BOTH layers' weights in one launch
    pack_frag2<<<(5 * NTILE * 64 + 255) / 256, 256, 0, stream>>>(
        l0w[0], l0w[2], l0w[4], l0w[6], l0w[1], l0w[3], l0w[5], l0w[7],
        l1w[0], l1w[2], l1w[4], l1w[6], l1w[1], l1w[3], l1w[5], l1w[7],
        Wf0h, Wf0l, bp0, Wf1h, Wf1l, bp1);

    // ---- CSR build: atomic-free deterministic bin sort ----
    hipMemsetAsync(deg, 0, NN * sizeof(int), stream);
    chunk_hist<<<NCHUNK, 256, 0, stream>>>(ei, deg, cmat);
    block_sum<<<NB, 256, 0, stream>>>(deg, partial);
    scan_partial<<<1, 64, 0, stream>>>(partial);
    block_scan<<<NB, 256, 0, stream>>>(deg, partial, roff, woff);
    bin_offsets<<<1, 128, 0, stream>>>(cmat, roff, omat);
    bin_scatter<<<NCHUNK, 256, 0, stream>>>(ei, omat, pairs);
    bin_sort<<<NBIN, 256, 0, stream>>>(pairs, roff, esrc);

    const int gemm_blocks = (NN + 127) / 128;    // 782, one block = 128 rows x all tiles
    const int attn_waves = (NN + 1) / 2;         // one node per half-wave
    const int attn_blocks = (attn_waves * 64 + 255) / 256;   // 12500

    // layer 0: gemm reads X fp32 directly (in-staging bf16 split)
    gemm_mfma<4, true><<<gemm_blocks, 256, 0, stream>>>(
        x, nullptr, Wf0h, Wf0l, bp0, qbh, sb, kvb);
    fused_attn<<<attn_blocks, 256, 0, stream>>>(qbh, sb, kvb, roff, esrc, (float*)nullptr, hh, hl);

    // layer 1 (attn writes only h0)
    gemm_mfma<1, false><<<gemm_blocks, 256, 0, stream>>>(
        hh, hl, Wf1h, Wf1l, bp1, qbh, sb, kvb);
    fused_attn<<<attn_blocks, 256, 0, stream>>>(qbh, sb, kvb, roff, esrc, h0,
                                                (unsigned short*)nullptr, (unsigned short*)nullptr);

    // output linear
    out_linear<<<(NN * OUT_DIM + 255) / 256, 256, 0, stream>>>(h0, Wout, bout, out);
}

// Round 10
// 418.526 us; speedup vs baseline: 1.7868x; 1.0424x over previous
//
#include <hip/hip_runtime.h>
#include <math.h>

#define NN 100000
#define EE 800000
#define IN_DIM 128
#define HID 32
#define HEADS 4
#define QKV 128         // HEADS*HID
#define COLS 416        // 3*QKV + HID (q|k|v|skip)
#define QBH_W 128       // q bf16 row (256 B)
#define SB_W 32         // skip fp32 row (128 B)
#define KV_W 256        // interleaved bf16: 32 groups of [k x4 | v x4] (512-B rows)
#define OUT_DIM 16
#define NB 98           // ceil(NN/1024) scan blocks
#define NTILE 26        // 416/16 col-tiles
#define NBIN 128        // dst-range bins for CSR sort
#define BINW 782        // ceil(NN/NBIN); 128*782 = 100096 >= NN
#define CH 2048         // edges per chunk
#define NCHUNK 391      // ceil(EE/CH)
// (1/sqrt(32)) * log2(e): pre-folded into q so p = exp2(part)
#define QSCALE 0.25503512f

typedef __attribute__((ext_vector_type(8))) _Float16 half8;
typedef __attribute__((ext_vector_type(4))) float floatx4;

__device__ __forceinline__ unsigned short f2bf(float f) {
    unsigned int u = __float_as_uint(f);
    unsigned int r = (u + 0x7FFF + ((u >> 16) & 1)) >> 16;   // RNE
    return (unsigned short)r;
}
__device__ __forceinline__ float bf2f(unsigned short h) {
    return __uint_as_float((unsigned int)h << 16);
}
__device__ __forceinline__ float bf_lo(unsigned int d) {
    return __uint_as_float(d << 16);
}
__device__ __forceinline__ float bf_hi(unsigned int d) {
    return __uint_as_float(d & 0xFFFF0000u);
}
__device__ __forceinline__ unsigned short f2h(float f) {
    _Float16 h = (_Float16)f;                  // v_cvt_f16_f32, RNE
    return __builtin_bit_cast(unsigned short, h);
}

// ---------------- fragment-pack BOTH layers' W (f16 single plane) + biases
// Wf[((c*26 + t)*64 + lane)*8 + j] = W[(c*32 + (lane>>4)*8 + j)][t*16 + (lane&15)]
// R21: f16 single-plane weights. GEMM outputs are rounded to single bf16
// for qbh/kvb anyway (2^-9 rel) -> f16 input rounding (2^-11) is below the
// already-accepted error floor; the 3-term split-bf16 bought nothing.
__device__ __forceinline__ void pack_one(
        const float* __restrict__ Wq, const float* __restrict__ Wk,
        const float* __restrict__ Wv, const float* __restrict__ Ws,
        const float* __restrict__ bq, const float* __restrict__ bk,
        const float* __restrict__ bv, const float* __restrict__ bs,
        unsigned short* __restrict__ Wf, float* __restrict__ bp,
        int K, int idx) {
    if (idx < COLS) {
        float b;
        if (idx < 128)      b = bq[idx];
        else if (idx < 256) b = bk[idx - 128];
        else if (idx < 384) b = bv[idx - 256];
        else                b = bs[idx - 384];
        bp[idx] = b;
    }
    int nch = K >> 5;
    if (idx >= nch * NTILE * 64) return;
    int lane = idx & 63;
    int tt = (idx >> 6) % NTILE;
    int c = idx / (NTILE * 64);
    int k0 = c * 32 + (lane >> 4) * 8;
    int col = tt * 16 + (lane & 15);
    #pragma unroll
    for (int j = 0; j < 8; ++j) {
        int k = k0 + j;
        float w;
        if (col < 128)      w = Wq[(size_t)k * 128 + col];
        else if (col < 256) w = Wk[(size_t)k * 128 + (col - 128)];
        else if (col < 384) w = Wv[(size_t)k * 128 + (col - 256)];
        else                w = Ws[(size_t)k * 32 + (col - 384)];
        Wf[(size_t)idx * 8 + j] = f2h(w);
    }
}

__global__ void pack_frag2(
        const float* __restrict__ Wq0, const float* __restrict__ Wk0,
        const float* __restrict__ Wv0, const float* __restrict__ Ws0,
        const float* __restrict__ bq0, const float* __restrict__ bk0,
        const float* __restrict__ bv0, const float* __restrict__ bs0,
        const float* __restrict__ Wq1, const float* __restrict__ Wk1,
        const float* __restrict__ Wv1, const float* __restrict__ Ws1,
        const float* __restrict__ bq1, const float* __restrict__ bk1,
        const float* __restrict__ bv1, const float* __restrict__ bs1,
        unsigned short* __restrict__ Wf0, float* __restrict__ bp0,
        unsigned short* __restrict__ Wf1, float* __restrict__ bp1) {
    const int L0N = 4 * NTILE * 64;   // 6656
    int gid = blockIdx.x * blockDim.x + threadIdx.x;
    if (gid < L0N) {
        pack_one(Wq0, Wk0, Wv0, Ws0, bq0, bk0, bv0, bs0, Wf0, bp0, 128, gid);
    } else {
        pack_one(Wq1, Wk1, Wv1, Ws1, bq1, bk1, bv1, bs1, Wf1, bp1, 32, gid - L0N);
    }
}

// ---------------- CSR build: ATOMIC-FREE deterministic bin sort ----------
__global__ __launch_bounds__(256) void chunk_hist(
        const int* __restrict__ ei, int* __restrict__ deg,
        int* __restrict__ cmat) {
    __shared__ int cnt[NBIN];
    const int t = threadIdx.x;
    const int c = blockIdx.x;
    const int c0 = c * CH;
    const int nc = min(CH, EE - c0);
    if (t < NBIN) cnt[t] = 0;
    __syncthreads();
    for (int i = t; i < nc; i += 256) {
        int d = ei[EE + c0 + i];
        atomicAdd(&deg[d], 1);
        atomicAdd(&cnt[d / BINW], 1);
    }
    __syncthreads();
    if (t < NBIN) cmat[c * NBIN + t] = cnt[t];
}

__global__ void block_sum(const int* __restrict__ deg, int* __restrict__ partial) {
    __shared__ int sdata[256];
    int b = blockIdx.x, t = threadIdx.x;
    int sum = 0;
    for (int i = t; i < 1024; i += 256) {
        int g = b * 1024 + i;
        if (g < NN) sum += deg[g];
    }
    sdata[t] = sum; __syncthreads();
    for (int s = 128; s > 0; s >>= 1) {
        if (t < s) sdata[t] += sdata[t + s];
        __syncthreads();
    }
    if (t == 0) partial[b] = sdata[0];
}

__global__ void scan_partial(int* __restrict__ partial) {
    int l = threadIdx.x;   // 64 threads
    int a = (l < NB) ? partial[l] : 0;
    int b = (l + 64 < NB) ? partial[l + 64] : 0;
    for (int off = 1; off < 64; off <<= 1) {
        int v = __shfl_up(a, off);
        if (l >= off) a += v;
    }
    int tot = __shfl(a, 63);
    for (int off = 1; off < 64; off <<= 1) {
        int v = __shfl_up(b, off);
        if (l >= off) b += v;
    }
    b += tot;
    int ea = __shfl_up(a, 1); if (l == 0) ea = 0;
    int eb = __shfl_up(b, 1); if (l == 0) eb = tot;
    if (l < NB) partial[l] = ea;
    if (l + 64 < NB) partial[l + 64] = eb;
}

__global__ void block_scan(const int* __restrict__ deg, const int* __restrict__ partial,
                           int* __restrict__ roff, int* __restrict__ woff) {
    __shared__ int ssum[256];
    int b = blockIdx.x, t = threadIdx.x;
    int base = b * 1024 + t * 4;
    int v[4]; int s = 0;
    #pragma unroll
    for (int i = 0; i < 4; ++i) {
        int g = base + i;
        v[i] = (g < NN) ? deg[g] : 0;
        s += v[i];
    }
    ssum[t] = s; __syncthreads();
    for (int off = 1; off < 256; off <<= 1) {
        int val = (t >= off) ? ssum[t - off] : 0;
        __syncthreads();
        ssum[t] += val;
        __syncthreads();
    }
    int excl = (t == 0) ? 0 : ssum[t - 1];
    excl += partial[b];
    #pragma unroll
    for (int i = 0; i < 4; ++i) {
        int g = base + i;
        if (g < NN) { roff[g] = excl; woff[g] = excl; }
        excl += v[i];
    }
    if (b == NB - 1 && t == 255) roff[NN] = EE;
}

__global__ void bin_offsets(const int* __restrict__ cmat, const int* __restrict__ roff,
                            int* __restrict__ omat) {
    int b = threadIdx.x;
    if (b >= NBIN) return;
    int d0 = b * BINW;
    int run = roff[d0 < NN ? d0 : NN];
    for (int c = 0; c < NCHUNK; ++c) {
        omat[c * NBIN + b] = run;
        run += cmat[c * NBIN + b];
    }
}

__global__ __launch_bounds__(256) void bin_scatter(
        const int* __restrict__ ei, const int* __restrict__ omat,
        int2* __restrict__ pairs) {
    __shared__ int cnt[NBIN], excl[NBIN], cur[NBIN], gbase[NBIN];
    __shared__ int2 stg[CH];
    __shared__ unsigned char binof[CH];
    const int t = threadIdx.x;
    const int c = blockIdx.x;
    const int c0 = c * CH;
    const int nc = min(CH, EE - c0);
    if (t < NBIN) cnt[t] = 0;
    __syncthreads();
    int msrc[8], mdst[8], mbin[8];
    #pragma unroll
    for (int i = 0; i < 8; ++i) {
        int idx = t + i * 256;
        if (idx < nc) {
            msrc[i] = ei[c0 + idx];
            mdst[i] = ei[EE + c0 + idx];
            mbin[i] = mdst[i] / BINW;
            atomicAdd(&cnt[mbin[i]], 1);
        }
    }
    __syncthreads();
    if (t < NBIN) excl[t] = cnt[t];
    __syncthreads();
    for (int off = 1; off < NBIN; off <<= 1) {
        int v = (t < NBIN && t >= off) ? excl[t - off] : 0;
        __syncthreads();
        if (t < NBIN) excl[t] += v;
        __syncthreads();
    }
    if (t < NBIN) {
        int e2 = excl[t] - cnt[t];
        excl[t] = e2; cur[t] = e2;
        gbase[t] = omat[c * NBIN + t];
    }
    __syncthreads();
    #pragma unroll
    for (int i = 0; i < 8; ++i) {
        int idx = t + i * 256;
        if (idx < nc) {
            int pos = atomicAdd(&cur[mbin[i]], 1);
            stg[pos] = make_int2(msrc[i], mdst[i]);
            binof[pos] = (unsigned char)mbin[i];
        }
    }
    __syncthreads();
    for (int i = t; i < nc; i += 256) {
        int b = binof[i];
        pairs[gbase[b] + (i - excl[b])] = stg[i];
    }
}

__global__ __launch_bounds__(256) void bin_sort(
        const int2* __restrict__ pairs, const int* __restrict__ roff,
        int* __restrict__ esrc) {
    __shared__ int cursor[BINW];     // 3.1 KB
    __shared__ int loc[8192];        // 32 KB (bin mean 6250, +24 sigma safe)
    const int b = blockIdx.x;
    const int t = threadIdx.x;
    const int d0 = b * BINW;
    const int d1 = (d0 + BINW < NN) ? d0 + BINW : NN;
    const int base = roff[d0];
    const int end  = roff[d1];
    const int cnt = end - base;
    for (int d = t; d < d1 - d0; d += 256) cursor[d] = roff[d0 + d] - base;
    __syncthreads();
    for (int i = t; i < cnt; i += 256) {
        int2 p = pairs[base + i];
        int pos = atomicAdd(&cursor[p.y - d0], 1);
        loc[pos] = p.x;
    }
    __syncthreads();
    for (int i = t; i < cnt; i += 256) esrc[base + i] = loc[i];
}

// ---------------- f16 single-pass MFMA GEMM, X staged once in LDS --------
// R21: one f16 MFMA per (W,X) pair (was 3 split-bf16). X single f16 plane
// in LDS (32 KB @K=128) -> 48 KB total -> 3 blocks/CU. F32 path converts
// fp32->f16 during staging; F16 path (layer 1) copies the f16 h plane.
template <int NCH, bool F32>
__global__ __launch_bounds__(256, 3) void gemm_mfma(
        const void* __restrict__ A0,
        const unsigned short* __restrict__ Wf,
        const float* __restrict__ bp, unsigned short* __restrict__ qbh,
        float* __restrict__ sb, unsigned short* __restrict__ kvb) {
    constexpr int K = NCH * 32;
    constexpr int ROWB = 2 * K;              // bytes per X row (f16)
    constexpr int SWZ = (NCH == 4) ? 7 : 3;  // row-XOR mask (<<4)
    __shared__ char xlds[128 * ROWB];        // single f16 plane
    __shared__ char olds[4][32][128];        // per-wave out staging
    const int tid = threadIdx.x;
    const int lane = tid & 63;
    const int wv = tid >> 6;
    const int m0b = blockIdx.x << 7;         // block's 128-row base
    const int ml = lane & 15;
    const int quad = lane >> 4;

    // ---- stage X into LDS (coalesced, XOR-swizzled) ----
    if constexpr (F32) {
        const char* X = (const char*)A0;     // fp32, row = 4*K bytes
        const int NPF = 128 * (K / 4);       // 16-B fp32 pieces
        for (int p = tid; p < NPF; p += 256) {
            int row = p / (K / 4);
            int pc = p % (K / 4);
            int grow = m0b + row;
            if (grow >= NN) grow = NN - 1;
            float4 v = *(const float4*)(X + (size_t)grow * (4 * K) + pc * 16);
            ushort4 h = {f2h(v.x), f2h(v.y), f2h(v.z), f2h(v.w)};
            int addr = row * ROWB + ((pc * 8) ^ ((row & SWZ) << 4));
            *(ushort4*)(xlds + addr) = h;
        }
    } else {
        const char* X = (const char*)A0;     // f16, row = ROWB bytes
        const int NP = 128 * ROWB / 16;
        for (int p = tid; p < NP; p += 256) {
            int gb = p * 16;
            int row = gb / ROWB;
            int col = gb & (ROWB - 1);
            int grow = m0b + row;
            if (grow >= NN) grow = NN - 1;
            uint4 d = *(const uint4*)(X + (size_t)grow * ROWB + col);
            *(uint4*)(xlds + row * ROWB + (col ^ ((row & SWZ) << 4))) = d;
        }
    }
    __syncthreads();

    const int m0 = m0b + (wv << 5);          // this wave's 32-row base
    const int rowL0 = (wv << 5) + ml;        // local row, half 0
    const int rowL1 = rowL0 + 16;            // local row, half 1
    char* myl = &olds[wv][0][0];

    // each wave: its 32 rows x ALL 7 column groups
    for (int g = 0; g < 7; ++g) {
        int tiles[4]; int ntl = 4; int gtype;     // 0=q, 1=kv, 2=skip
        if (g < 2) {
            gtype = 0;
            #pragma unroll
            for (int i = 0; i < 4; ++i) tiles[i] = 4 * g + i;
        } else if (g < 6) {
            gtype = 1;
            int j = g - 2;
            tiles[0] = 8 + 2 * j; tiles[1] = 9 + 2 * j;
            tiles[2] = 16 + 2 * j; tiles[3] = 17 + 2 * j;
        } else {
            gtype = 2; ntl = 2;
            tiles[0] = 24; tiles[1] = 25; tiles[2] = 24; tiles[3] = 25;
        }

        floatx4 acc[2][4] = {};

        #pragma unroll
        for (int c = 0; c < NCH; ++c) {
            int colb = (c * 64 + quad * 16);
            int a0 = rowL0 * ROWB + (colb ^ ((rowL0 & SWZ) << 4));
            int a1 = rowL1 * ROWB + (colb ^ ((rowL1 & SWZ) << 4));
            half8 x0 = *(const half8*)(xlds + a0);
            half8 x1 = *(const half8*)(xlds + a1);
            #pragma unroll
            for (int t = 0; t < 4; ++t) {
                if (t < ntl) {
                    size_t boff = (((size_t)c * NTILE + tiles[t]) * 64 + lane) * 8;
                    half8 w = *(const half8*)(Wf + boff);
                    acc[0][t] = __builtin_amdgcn_mfma_f32_16x16x32_f16(w, x0, acc[0][t], 0, 0, 0);
                    acc[1][t] = __builtin_amdgcn_mfma_f32_16x16x32_f16(w, x1, acc[1][t], 0, 0, 0);
                }
            }
        }

        // ---- stage into wave-private LDS in FINAL byte order (XOR pitch-128) ----
        #pragma unroll
        for (int t = 0; t < 4; ++t) {
            if (t >= ntl) break;
            int tg = tiles[t];
            int c0 = (tg << 4) + (quad << 2);
            float4 b4 = *(const float4*)(bp + c0);
            #pragma unroll
            for (int mt = 0; mt < 2; ++mt) {
                int row = mt * 16 + ml;
                int sz = (row & 7) << 4;
                float v0 = acc[mt][t][0] + b4.x;
                float v1 = acc[mt][t][1] + b4.y;
                float v2 = acc[mt][t][2] + b4.z;
                float v3 = acc[mt][t][3] + b4.w;
                if (gtype == 2) {                  // skip fp32
                    *(float4*)(myl + row * 128 + ((64 * t + 16 * quad) ^ sz)) =
                        make_float4(v0, v1, v2, v3);
                } else {
                    ushort4 u = {f2bf(v0), f2bf(v1), f2bf(v2), f2bf(v3)};
                    int off;
                    if (gtype == 0) off = 32 * t + 8 * quad;                 // q linear
                    else off = 64 * (t & 1) + 16 * quad + 8 * (t >> 1);      // kv interleave
                    *(ushort4*)(myl + row * 128 + (off ^ sz)) = u;
                }
            }
        }
        // wave-private RAW/WAR: DS pipe is in-order per wave; compiler
        // inserts lgkmcnt waits. No barrier needed.

        // ---- linear read-back + full-line global stores ----
        const int lr = lane >> 3;          // 0..7 row within page
        const int lc = (lane & 7) * 16;    // byte offset in 128-B chunk
        #pragma unroll
        for (int i = 0; i < 4; ++i) {
            int row = i * 8 + lr;
            uint4 d = *(const uint4*)(myl + row * 128 + (lc ^ (lr << 4)));
            int node = m0 + row;
            if (node < NN) {
                char* dst;
                if (gtype == 0)      dst = (char*)qbh + (size_t)node * 256 + g * 128 + lc;
                else if (gtype == 1) dst = (char*)kvb + (size_t)node * 512 + (g - 2) * 128 + lc;
                else                 dst = (char*)sb + (size_t)node * 128 + lc;
                *(uint4*)dst = d;
            }
        }
    }
}

// ---------------- fused attention: ONE NODE PER HALF-WAVE ----------------
// R16 structure: wave = 2 nodes, 8 independent gathers in flight per wave.
// NO-MAX softmax (logits bounded, fp32 exact). Layer-0 writes h as ONE f16
// plane (layer-1 GEMM input); layer-1 writes h0 fp32.
#define ATTN_STEP(u) {                                                       \
    float k0 = bf_lo((u).x), k1 = bf_hi((u).x);                              \
    float k2 = bf_lo((u).y), k3 = bf_hi((u).y);                              \
    float v0 = bf_lo((u).z), v1 = bf_hi((u).z);                              \
    float v2 = bf_lo((u).w), v3 = bf_hi((u).w);                              \
    float part = q4.x * k0 + q4.y * k1 + q4.z * k2 + q4.w * k3;              \
    part += __shfl_xor(part, 1);                                             \
    part += __shfl_xor(part, 2);                                             \
    part += __shfl_xor(part, 4);                                             \
    float p = exp2f(part);                                                   \
    s += p;                                                                  \
    acc.x += p * v0;                                                         \
    acc.y += p * v1;                                                         \
    acc.z += p * v2;                                                         \
    acc.w += p * v3; }

__global__ __launch_bounds__(256) void fused_attn(
        const unsigned short* __restrict__ qbh, const float* __restrict__ sb,
        const unsigned short* __restrict__ kvb,
        const int* __restrict__ roff, const int* __restrict__ esrc,
        float* __restrict__ hout,
        unsigned short* __restrict__ hf) {
    const int lane = threadIdx.x & 63;
    const int w = (blockIdx.x * blockDim.x + threadIdx.x) >> 6;   // wave id
    const int hw = lane >> 5;
    const int n = 2 * w + hw;          // this half-wave's node
    if (n >= NN) return;               // NN even: whole halves retire
    const int kl = lane & 31;

    ushort4 qu = *(const ushort4*)(qbh + (size_t)n * QBH_W + 4 * kl);
    float4 q4 = make_float4(bf2f(qu.x) * QSCALE, bf2f(qu.y) * QSCALE,
                            bf2f(qu.z) * QSCALE, bf2f(qu.w) * QSCALE);
    // hoist skip row (redundant 4x read, coalesced, overlaps gather loop)
    float4 sk = *(const float4*)(sb + (size_t)n * SB_W + 4 * (kl & 7));

    float s = 0.f;
    float4 acc = make_float4(0.f, 0.f, 0.f, 0.f);
    const int e0 = roff[n];
    const int cnt = roff[n + 1] - e0;
    int i = 0;
    for (; i + 4 <= cnt; i += 4) {
        int b0 = esrc[e0 + i];
        int b1 = esrc[e0 + i + 1];
        int b2 = esrc[e0 + i + 2];
        int b3 = esrc[e0 + i + 3];
        uint4 u0 = *(const uint4*)(kvb + (size_t)b0 * KV_W + 8 * kl);
        uint4 u1 = *(const uint4*)(kvb + (size_t)b1 * KV_W + 8 * kl);
        uint4 u2 = *(const uint4*)(kvb + (size_t)b2 * KV_W + 8 * kl);
        uint4 u3 = *(const uint4*)(kvb + (size_t)b3 * KV_W + 8 * kl);
        ATTN_STEP(u0); ATTN_STEP(u1); ATTN_STEP(u2); ATTN_STEP(u3);
    }
    for (; i < cnt; ++i) {
        int b0 = esrc[e0 + i];
        uint4 u0 = *(const uint4*)(kvb + (size_t)b0 * KV_W + 8 * kl);
        ATTN_STEP(u0);
    }

    float inv = (s > 0.f) ? 1.f / s : 0.f;
    float4 o;
    o.x = acc.x * inv; o.y = acc.y * inv; o.z = acc.z * inv; o.w = acc.w * inv;
    // sum over heads (head bits of kl are bits 3,4; xor 8/16 stay in-half)
    o.x += __shfl_xor(o.x, 8);  o.y += __shfl_xor(o.y, 8);  o.z += __shfl_xor(o.z, 8);  o.w += __shfl_xor(o.w, 8);
    o.x += __shfl_xor(o.x, 16); o.y += __shfl_xor(o.y, 16); o.z += __shfl_xor(o.z, 16); o.w += __shfl_xor(o.w, 16);
    if (kl < 8) {
        float4 rr;
        rr.x = fmaxf(o.x * 0.25f + sk.x, 0.f);
        rr.y = fmaxf(o.y * 0.25f + sk.y, 0.f);
        rr.z = fmaxf(o.z * 0.25f + sk.z, 0.f);
        rr.w = fmaxf(o.w * 0.25f + sk.w, 0.f);
        int c0 = 4 * kl;
        if (hout)
            *(float4*)(hout + (size_t)n * HID + c0) = rr;
        if (hf) {
            ushort4 uh = {f2h(rr.x), f2h(rr.y), f2h(rr.z), f2h(rr.w)};
            *(ushort4*)(hf + (size_t)n * HID + c0) = uh;
        }
    }
}

// ---------------- final linear: out = h @ Wout + bout --------------------
__global__ void out_linear(const float* __restrict__ h, const float* __restrict__ Wout,
                           const float* __restrict__ bout, float* __restrict__ out) {
    int idx = blockIdx.x * blockDim.x + threadIdx.x;
    if (idx >= NN * OUT_DIM) return;
    int n = idx >> 4;
    int j = idx & 15;
    float accv = bout[j];
    #pragma unroll
    for (int k = 0; k < HID; ++k)
        accv += h[(size_t)n * HID + k] * Wout[k * OUT_DIM + j];
    out[idx] = accv;
}

extern "C" void kernel_launch(void* const* d_in, const int* in_sizes, int n_in,
                              void* d_out, int out_size, void* d_ws, size_t ws_size,
                              hipStream_t stream) {
    const float* x  = (const float*)d_in[0];
    const int*   ei = (const int*)d_in[1];
    const float* l0w[8]; const float* l1w[8];
    for (int i = 0; i < 8; ++i) { l0w[i] = (const float*)d_in[2 + i]; l1w[i] = (const float*)d_in[10 + i]; }
    const float* Wout = (const float*)d_in[18];
    const float* bout = (const float*)d_in[19];
    float* out = (float*)d_out;

    // workspace layout
    float* ws = (float*)d_ws;
    float* sb   = ws;                           // NN*32 floats
    float* h0   = sb + (size_t)NN * SB_W;       // NN*32
    float* bp0  = h0 + (size_t)NN * HID;        // 416
    float* bp1  = bp0 + COLS;                   // 416
    unsigned short* qbh  = (unsigned short*)(bp1 + COLS);    // NN*128 bf16
    unsigned short* kvb  = qbh + (size_t)NN * QBH_W;         // NN*256 bf16
    unsigned short* hf   = kvb + (size_t)NN * KV_W;          // NN*32 f16
    unsigned short* Wf0  = hf + (size_t)NN * HID;            // 4*26*64*8
    unsigned short* Wf1  = Wf0 + 4 * NTILE * 64 * 8;         // 1*26*64*8
    int* ibase  = (int*)(Wf1 + NTILE * 64 * 8);
    int* deg     = ibase;                       // NN
    int* roff    = deg + NN;                    // NN+1
    int* woff    = roff + NN + 1;               // NN
    int* partial = woff + NN;                   // NB
    int* esrc    = partial + NB;                // EE
    int* cmat    = esrc + EE;                   // NCHUNK*NBIN (~200KB)
    int* omat    = cmat + NCHUNK * NBIN;        // NCHUNK*NBIN
    int2* pairs  = (int2*)(omat + NCHUNK * NBIN);  // EE int2 (6.4 MB)

    // pack BOTH layers' weights in one launch
    pack_frag2<<<(5 * NTILE * 64 + 255) / 256, 256, 0, stream>>>(
        l0w[0], l0w[2], l0w[4], l0w[6], l0w[1], l0w[3], l0w[5], l0w[7],
        l1w[0], l1w[2], l1w[4], l1w[6], l1w[1], l1w[3], l1w[5], l1w[7],
        Wf0, bp0, Wf1, bp1);

    // ---- CSR build: atomic-free deterministic bin sort ----
    hipMemsetAsync(deg, 0, NN * sizeof(int), stream);
    chunk_hist<<<NCHUNK, 256, 0, stream>>>(ei, deg, cmat);
    block_sum<<<NB, 256, 0, stream>>>(deg, partial);
    scan_partial<<<1, 64, 0, stream>>>(partial);
    block_scan<<<NB, 256, 0, stream>>>(deg, partial, roff, woff);
    bin_offsets<<<1, 128, 0, stream>>>(cmat, roff, omat);
    bin_scatter<<<NCHUNK, 256, 0, stream>>>(ei, omat, pairs);
    bin_sort<<<NBIN, 256, 0, stream>>>(pairs, roff, esrc);

    const int gemm_blocks = (NN + 127) / 128;    // 782, one block = 128 rows x all tiles
    const int attn_waves = (NN + 1) / 2;         // one node per half-wave
    const int attn_blocks = (attn_waves * 64 + 255) / 256;   // 12500

    // layer 0: gemm reads X fp32 directly (in-staging f16 convert)
    gemm_mfma<4, true><<<gemm_blocks, 256, 0, stream>>>(
        x, Wf0, bp0, qbh, sb, kvb);
    fused_attn<<<attn_blocks, 256, 0, stream>>>(qbh, sb, kvb, roff, esrc,
                                                (float*)nullptr, hf);

    // layer 1: gemm reads h f16 plane
    gemm_mfma<1, false><<<gemm_blocks, 256, 0, stream>>>(
        hf, Wf1, bp1, qbh, sb, kvb);
    fused_attn<<<attn_blocks, 256, 0, stream>>>(qbh, sb, kvb, roff, esrc, h0,
                                                (unsigned short*)nullptr);

    // output linear
    out_linear<<<(NN * OUT_DIM + 255) / 256, 256, 0, stream>>>(h0, Wout, bout, out);
}

// Round 11
// 357.357 us; speedup vs baseline: 2.0926x; 1.1712x over previous
//
#include <hip/hip_runtime.h>
#include <math.h>

#define NN 100000
#define EE 800000
#define IN_DIM 128
#define HID 32
#define HEADS 4
#define QKV 128         // HEADS*HID
#define COLS 416        // 3*QKV + HID (q|k|v|skip)
#define QBH_W 128       // q bf16 row (256 B)
#define SB_W 32         // skip fp32 row (128 B)
#define KV_W 256        // interleaved bf16: 32 groups of [k x4 | v x4] (512-B rows)
#define OUT_DIM 16
#define NTILE 26        // 416/16 col-tiles
#define NBIN 128        // dst-range bins for CSR sort
#define BINW 782        // ceil(NN/NBIN); 128*782 = 100096 >= NN
#define CH 2048         // edges per chunk
#define NCHUNK 391      // ceil(EE/CH)
// (1/sqrt(32)) * log2(e): pre-folded into q so p = exp2(part)
#define QSCALE 0.25503512f

typedef __attribute__((ext_vector_type(8))) _Float16 half8;
typedef __attribute__((ext_vector_type(4))) float floatx4;

__device__ __forceinline__ unsigned short f2bf(float f) {
    unsigned int u = __float_as_uint(f);
    unsigned int r = (u + 0x7FFF + ((u >> 16) & 1)) >> 16;   // RNE
    return (unsigned short)r;
}
__device__ __forceinline__ float bf2f(unsigned short h) {
    return __uint_as_float((unsigned int)h << 16);
}
__device__ __forceinline__ float bf_lo(unsigned int d) {
    return __uint_as_float(d << 16);
}
__device__ __forceinline__ float bf_hi(unsigned int d) {
    return __uint_as_float(d & 0xFFFF0000u);
}
__device__ __forceinline__ unsigned short f2h(float f) {
    _Float16 h = (_Float16)f;                  // v_cvt_f16_f32, RNE
    return __builtin_bit_cast(unsigned short, h);
}

// ---------------- fragment-pack BOTH layers' W (f16 single plane) + biases
// Wf[((c*26 + t)*64 + lane)*8 + j] = W[(c*32 + (lane>>4)*8 + j)][t*16 + (lane&15)]
__device__ __forceinline__ void pack_one(
        const float* __restrict__ Wq, const float* __restrict__ Wk,
        const float* __restrict__ Wv, const float* __restrict__ Ws,
        const float* __restrict__ bq, const float* __restrict__ bk,
        const float* __restrict__ bv, const float* __restrict__ bs,
        unsigned short* __restrict__ Wf, float* __restrict__ bp,
        int K, int idx) {
    if (idx < COLS) {
        float b;
        if (idx < 128)      b = bq[idx];
        else if (idx < 256) b = bk[idx - 128];
        else if (idx < 384) b = bv[idx - 256];
        else                b = bs[idx - 384];
        bp[idx] = b;
    }
    int nch = K >> 5;
    if (idx >= nch * NTILE * 64) return;
    int lane = idx & 63;
    int tt = (idx >> 6) % NTILE;
    int c = idx / (NTILE * 64);
    int k0 = c * 32 + (lane >> 4) * 8;
    int col = tt * 16 + (lane & 15);
    #pragma unroll
    for (int j = 0; j < 8; ++j) {
        int k = k0 + j;
        float w;
        if (col < 128)      w = Wq[(size_t)k * 128 + col];
        else if (col < 256) w = Wk[(size_t)k * 128 + (col - 128)];
        else if (col < 384) w = Wv[(size_t)k * 128 + (col - 256)];
        else                w = Ws[(size_t)k * 32 + (col - 384)];
        Wf[(size_t)idx * 8 + j] = f2h(w);
    }
}

__global__ void pack_frag2(
        const float* __restrict__ Wq0, const float* __restrict__ Wk0,
        const float* __restrict__ Wv0, const float* __restrict__ Ws0,
        const float* __restrict__ bq0, const float* __restrict__ bk0,
        const float* __restrict__ bv0, const float* __restrict__ bs0,
        const float* __restrict__ Wq1, const float* __restrict__ Wk1,
        const float* __restrict__ Wv1, const float* __restrict__ Ws1,
        const float* __restrict__ bq1, const float* __restrict__ bk1,
        const float* __restrict__ bv1, const float* __restrict__ bs1,
        unsigned short* __restrict__ Wf0, float* __restrict__ bp0,
        unsigned short* __restrict__ Wf1, float* __restrict__ bp1) {
    const int L0N = 4 * NTILE * 64;   // 6656
    int gid = blockIdx.x * blockDim.x + threadIdx.x;
    if (gid < L0N) {
        pack_one(Wq0, Wk0, Wv0, Ws0, bq0, bk0, bv0, bs0, Wf0, bp0, 128, gid);
    } else {
        pack_one(Wq1, Wk1, Wv1, Ws1, bq1, bk1, bv1, bs1, Wf1, bp1, 32, gid - L0N);
    }
}

// ---------------- CSR build: ATOMIC-FREE deterministic bin sort ----------
// R22: the NN-wide deg/scan chain is gone -- bin_sort derives roff from
// its local per-dst histogram + the bin base. bin_offsets' serial
// 391-iteration single-block loop replaced by a 128-block block-scan.

// one block per 2048-edge chunk: LDS 128-bin hist -> cmat row.
__global__ __launch_bounds__(256) void chunk_hist(
        const int* __restrict__ ei, int* __restrict__ cmat) {
    __shared__ int cnt[NBIN];
    const int t = threadIdx.x;
    const int c = blockIdx.x;
    const int c0 = c * CH;
    const int nc = min(CH, EE - c0);
    if (t < NBIN) cnt[t] = 0;
    __syncthreads();
    for (int i = t; i < nc; i += 256)
        atomicAdd(&cnt[ei[EE + c0 + i] / BINW], 1);
    __syncthreads();
    if (t < NBIN) cmat[c * NBIN + t] = cnt[t];
}

// 1 block, 128 threads: per-bin totals (coalesced row reads) + 128-wide
// exclusive scan -> bbase[0..128].
__global__ void btot_scan(const int* __restrict__ cmat, int* __restrict__ bbase) {
    __shared__ int sc[NBIN];
    int b = threadIdx.x;   // 128
    int s = 0;
    for (int c = 0; c < NCHUNK; ++c) s += cmat[c * NBIN + b];
    sc[b] = s;
    __syncthreads();
    for (int off = 1; off < NBIN; off <<= 1) {
        int v = (b >= off) ? sc[b - off] : 0;
        __syncthreads();
        sc[b] += v;
        __syncthreads();
    }
    bbase[b] = sc[b] - s;      // exclusive
    if (b == NBIN - 1) bbase[NBIN] = sc[NBIN - 1];
}

// 128 blocks (one per bin): block-scan over the 391 chunk counts ->
// omat[c][b] = global write base for chunk c's bin-b run.
__global__ __launch_bounds__(256) void bin_prefix(
        const int* __restrict__ cmat, const int* __restrict__ bbase,
        int* __restrict__ omat) {
    __shared__ int ssum[256];
    const int b = blockIdx.x;
    const int t = threadIdx.x;
    const int bb = bbase[b];
    int c0 = 2 * t;
    int v0 = (c0 < NCHUNK) ? cmat[(size_t)c0 * NBIN + b] : 0;
    int v1 = (c0 + 1 < NCHUNK) ? cmat[(size_t)(c0 + 1) * NBIN + b] : 0;
    int s = v0 + v1;
    ssum[t] = s;
    __syncthreads();
    for (int off = 1; off < 256; off <<= 1) {
        int v = (t >= off) ? ssum[t - off] : 0;
        __syncthreads();
        ssum[t] += v;
        __syncthreads();
    }
    int excl = ssum[t] - s;
    if (c0 < NCHUNK) omat[(size_t)c0 * NBIN + b] = bb + excl;
    if (c0 + 1 < NCHUNK) omat[(size_t)(c0 + 1) * NBIN + b] = bb + excl + v0;
}

// per chunk: LDS bin-sort, write each bin's run contiguously at its
// precomputed offset. Zero contended global atomics.
__global__ __launch_bounds__(256) void bin_scatter(
        const int* __restrict__ ei, const int* __restrict__ omat,
        int2* __restrict__ pairs) {
    __shared__ int cnt[NBIN], excl[NBIN], cur[NBIN], gbase[NBIN];
    __shared__ int2 stg[CH];
    __shared__ unsigned char binof[CH];
    const int t = threadIdx.x;
    const int c = blockIdx.x;
    const int c0 = c * CH;
    const int nc = min(CH, EE - c0);
    if (t < NBIN) cnt[t] = 0;
    __syncthreads();
    int msrc[8], mdst[8], mbin[8];
    #pragma unroll
    for (int i = 0; i < 8; ++i) {
        int idx = t + i * 256;
        if (idx < nc) {
            msrc[i] = ei[c0 + idx];
            mdst[i] = ei[EE + c0 + idx];
            mbin[i] = mdst[i] / BINW;
            atomicAdd(&cnt[mbin[i]], 1);
        }
    }
    __syncthreads();
    if (t < NBIN) excl[t] = cnt[t];
    __syncthreads();
    for (int off = 1; off < NBIN; off <<= 1) {
        int v = (t < NBIN && t >= off) ? excl[t - off] : 0;
        __syncthreads();
        if (t < NBIN) excl[t] += v;
        __syncthreads();
    }
    if (t < NBIN) {
        int e2 = excl[t] - cnt[t];
        excl[t] = e2; cur[t] = e2;
        gbase[t] = omat[c * NBIN + t];
    }
    __syncthreads();
    #pragma unroll
    for (int i = 0; i < 8; ++i) {
        int idx = t + i * 256;
        if (idx < nc) {
            int pos = atomicAdd(&cur[mbin[i]], 1);
            stg[pos] = make_int2(msrc[i], mdst[i]);
            binof[pos] = (unsigned char)mbin[i];
        }
    }
    __syncthreads();
    for (int i = t; i < nc; i += 256) {
        int b = binof[i];
        pairs[gbase[b] + (i - excl[b])] = stg[i];
    }
}

// one block per bin: LDS per-dst histogram + block scan -> roff AND the
// dst-grouped esrc. Replaces the old NN-wide deg/scan chain entirely.
__global__ __launch_bounds__(256) void bin_sort(
        const int2* __restrict__ pairs, const int* __restrict__ bbase,
        int* __restrict__ roff, int* __restrict__ esrc) {
    __shared__ int hist[BINW + 2];   // counts -> exclusive prefix -> cursor
    __shared__ int ssum[256];
    __shared__ int loc[8192];        // 32 KB (bin mean 6250, +24 sigma safe)
    const int b = blockIdx.x;
    const int t = threadIdx.x;
    const int d0 = b * BINW;
    const int nd = (d0 + BINW < NN) ? BINW : (NN - d0);
    const int base = bbase[b];
    const int cnt = bbase[b + 1] - base;
    for (int d = t; d < nd; d += 256) hist[d] = 0;
    __syncthreads();
    for (int i = t; i < cnt; i += 256)
        atomicAdd(&hist[pairs[base + i].y - d0], 1);
    __syncthreads();
    // block scan over nd (<=782) dst counts: 4 elems/thread + 256-scan
    int bi = t * 4;
    int v[4]; int s = 0;
    #pragma unroll
    for (int i = 0; i < 4; ++i) {
        int idx = bi + i;
        v[i] = (idx < nd) ? hist[idx] : 0;
        s += v[i];
    }
    ssum[t] = s;
    __syncthreads();
    for (int off = 1; off < 256; off <<= 1) {
        int val = (t >= off) ? ssum[t - off] : 0;
        __syncthreads();
        ssum[t] += val;
        __syncthreads();
    }
    int run = ssum[t] - s;
    #pragma unroll
    for (int i = 0; i < 4; ++i) {
        int idx = bi + i;
        if (idx < nd) {
            hist[idx] = run;                 // cursor start
            roff[d0 + idx] = base + run;
            run += v[i];
        }
    }
    if (b == NBIN - 1 && t == 0) roff[NN] = EE;
    __syncthreads();
    for (int i = t; i < cnt; i += 256) {
        int2 p = pairs[base + i];
        int pos = atomicAdd(&hist[p.y - d0], 1);
        loc[pos] = p.x;
    }
    __syncthreads();
    for (int i = t; i < cnt; i += 256) esrc[base + i] = loc[i];
}

// ---------------- f16 single-pass MFMA GEMM, X staged once in LDS --------
template <int NCH, bool F32>
__global__ __launch_bounds__(256, 3) void gemm_mfma(
        const void* __restrict__ A0,
        const unsigned short* __restrict__ Wf,
        const float* __restrict__ bp, unsigned short* __restrict__ qbh,
        float* __restrict__ sb, unsigned short* __restrict__ kvb) {
    constexpr int K = NCH * 32;
    constexpr int ROWB = 2 * K;              // bytes per X row (f16)
    constexpr int SWZ = (NCH == 4) ? 7 : 3;  // row-XOR mask (<<4)
    __shared__ char xlds[128 * ROWB];        // single f16 plane
    __shared__ char olds[4][32][128];        // per-wave out staging
    const int tid = threadIdx.x;
    const int lane = tid & 63;
    const int wv = tid >> 6;
    const int m0b = blockIdx.x << 7;         // block's 128-row base
    const int ml = lane & 15;
    const int quad = lane >> 4;

    // ---- stage X into LDS (coalesced, XOR-swizzled) ----
    if constexpr (F32) {
        const char* X = (const char*)A0;     // fp32, row = 4*K bytes
        const int NPF = 128 * (K / 4);       // 16-B fp32 pieces
        for (int p = tid; p < NPF; p += 256) {
            int row = p / (K / 4);
            int pc = p % (K / 4);
            int grow = m0b + row;
            if (grow >= NN) grow = NN - 1;
            float4 v = *(const float4*)(X + (size_t)grow * (4 * K) + pc * 16);
            ushort4 h = {f2h(v.x), f2h(v.y), f2h(v.z), f2h(v.w)};
            int addr = row * ROWB + ((pc * 8) ^ ((row & SWZ) << 4));
            *(ushort4*)(xlds + addr) = h;
        }
    } else {
        const char* X = (const char*)A0;     // f16, row = ROWB bytes
        const int NP = 128 * ROWB / 16;
        for (int p = tid; p < NP; p += 256) {
            int gb = p * 16;
            int row = gb / ROWB;
            int col = gb & (ROWB - 1);
            int grow = m0b + row;
            if (grow >= NN) grow = NN - 1;
            uint4 d = *(const uint4*)(X + (size_t)grow * ROWB + col);
            *(uint4*)(xlds + row * ROWB + (col ^ ((row & SWZ) << 4))) = d;
        }
    }
    __syncthreads();

    const int m0 = m0b + (wv << 5);          // this wave's 32-row base
    const int rowL0 = (wv << 5) + ml;        // local row, half 0
    const int rowL1 = rowL0 + 16;            // local row, half 1
    char* myl = &olds[wv][0][0];

    // each wave: its 32 rows x ALL 7 column groups
    for (int g = 0; g < 7; ++g) {
        int tiles[4]; int ntl = 4; int gtype;     // 0=q, 1=kv, 2=skip
        if (g < 2) {
            gtype = 0;
            #pragma unroll
            for (int i = 0; i < 4; ++i) tiles[i] = 4 * g + i;
        } else if (g < 6) {
            gtype = 1;
            int j = g - 2;
            tiles[0] = 8 + 2 * j; tiles[1] = 9 + 2 * j;
            tiles[2] = 16 + 2 * j; tiles[3] = 17 + 2 * j;
        } else {
            gtype = 2; ntl = 2;
            tiles[0] = 24; tiles[1] = 25; tiles[2] = 24; tiles[3] = 25;
        }

        floatx4 acc[2][4] = {};

        #pragma unroll
        for (int c = 0; c < NCH; ++c) {
            int colb = (c * 64 + quad * 16);
            int a0 = rowL0 * ROWB + (colb ^ ((rowL0 & SWZ) << 4));
            int a1 = rowL1 * ROWB + (colb ^ ((rowL1 & SWZ) << 4));
            half8 x0 = *(const half8*)(xlds + a0);
            half8 x1 = *(const half8*)(xlds + a1);
            #pragma unroll
            for (int t = 0; t < 4; ++t) {
                if (t < ntl) {
                    size_t boff = (((size_t)c * NTILE + tiles[t]) * 64 + lane) * 8;
                    half8 w = *(const half8*)(Wf + boff);
                    acc[0][t] = __builtin_amdgcn_mfma_f32_16x16x32_f16(w, x0, acc[0][t], 0, 0, 0);
                    acc[1][t] = __builtin_amdgcn_mfma_f32_16x16x32_f16(w, x1, acc[1][t], 0, 0, 0);
                }
            }
        }

        // ---- stage into wave-private LDS in FINAL byte order (XOR pitch-128) ----
        #pragma unroll
        for (int t = 0; t < 4; ++t) {
            if (t >= ntl) break;
            int tg = tiles[t];
            int c0 = (tg << 4) + (quad << 2);
            float4 b4 = *(const float4*)(bp + c0);
            #pragma unroll
            for (int mt = 0; mt < 2; ++mt) {
                int row = mt * 16 + ml;
                int sz = (row & 7) << 4;
                float v0 = acc[mt][t][0] + b4.x;
                float v1 = acc[mt][t][1] + b4.y;
                float v2 = acc[mt][t][2] + b4.z;
                float v3 = acc[mt][t][3] + b4.w;
                if (gtype == 2) {                  // skip fp32
                    *(float4*)(myl + row * 128 + ((64 * t + 16 * quad) ^ sz)) =
                        make_float4(v0, v1, v2, v3);
                } else {
                    ushort4 u = {f2bf(v0), f2bf(v1), f2bf(v2), f2bf(v3)};
                    int off;
                    if (gtype == 0) off = 32 * t + 8 * quad;                 // q linear
                    else off = 64 * (t & 1) + 16 * quad + 8 * (t >> 1);      // kv interleave
                    *(ushort4*)(myl + row * 128 + (off ^ sz)) = u;
                }
            }
        }
        // wave-private RAW/WAR: DS pipe is in-order per wave; compiler
        // inserts lgkmcnt waits. No barrier needed.

        // ---- linear read-back + full-line global stores ----
        const int lr = lane >> 3;          // 0..7 row within page
        const int lc = (lane & 7) * 16;    // byte offset in 128-B chunk
        #pragma unroll
        for (int i = 0; i < 4; ++i) {
            int row = i * 8 + lr;
            uint4 d = *(const uint4*)(myl + row * 128 + (lc ^ (lr << 4)));
            int node = m0 + row;
            if (node < NN) {
                char* dst;
                if (gtype == 0)      dst = (char*)qbh + (size_t)node * 256 + g * 128 + lc;
                else if (gtype == 1) dst = (char*)kvb + (size_t)node * 512 + (g - 2) * 128 + lc;
                else                 dst = (char*)sb + (size_t)node * 128 + lc;
                *(uint4*)dst = d;
            }
        }
    }
}

// ---------------- fused attention: ONE NODE PER HALF-WAVE ----------------
// R16 structure. FINAL=false: layer 0, writes h as one f16 plane.
// FINAL=true: layer 1, fuses the output linear (h @ Wout + bout) via a
// 1-KB LDS h-buffer -- h0 round-trip and out_linear kernel eliminated.
#define ATTN_STEP(u) {                                                       \
    float k0 = bf_lo((u).x), k1 = bf_hi((u).x);                              \
    float k2 = bf_lo((u).y), k3 = bf_hi((u).y);                              \
    float v0 = bf_lo((u).z), v1 = bf_hi((u).z);                              \
    float v2 = bf_lo((u).w), v3 = bf_hi((u).w);                              \
    float part = q4.x * k0 + q4.y * k1 + q4.z * k2 + q4.w * k3;              \
    part += __shfl_xor(part, 1);                                             \
    part += __shfl_xor(part, 2);                                             \
    part += __shfl_xor(part, 4);                                             \
    float p = exp2f(part);                                                   \
    s += p;                                                                  \
    acc.x += p * v0;                                                         \
    acc.y += p * v1;                                                         \
    acc.z += p * v2;                                                         \
    acc.w += p * v3; }

template <bool FINAL>
__global__ __launch_bounds__(256) void fused_attn(
        const unsigned short* __restrict__ qbh, const float* __restrict__ sb,
        const unsigned short* __restrict__ kvb,
        const int* __restrict__ roff, const int* __restrict__ esrc,
        unsigned short* __restrict__ hf,
        const float* __restrict__ Wout, const float* __restrict__ bout,
        float* __restrict__ outp) {
    __shared__ float hbuf[8][32];      // FINAL only: block's 8 node h rows
    const int tid = threadIdx.x;
    const int lane = tid & 63;
    const int w = (blockIdx.x * blockDim.x + tid) >> 6;   // wave id
    const int hw = lane >> 5;
    const int n = 2 * w + hw;          // this half-wave's node
    // NN = attn_blocks*8 exactly -> n < NN always; guard is never-taken
    // (kept for safety; never diverges at the FINAL barrier).
    if (n < NN) {
    const int kl = lane & 31;

    ushort4 qu = *(const ushort4*)(qbh + (size_t)n * QBH_W + 4 * kl);
    float4 q4 = make_float4(bf2f(qu.x) * QSCALE, bf2f(qu.y) * QSCALE,
                            bf2f(qu.z) * QSCALE, bf2f(qu.w) * QSCALE);
    // hoist skip row (redundant 4x read, coalesced, overlaps gather loop)
    float4 sk = *(const float4*)(sb + (size_t)n * SB_W + 4 * (kl & 7));

    float s = 0.f;
    float4 acc = make_float4(0.f, 0.f, 0.f, 0.f);
    const int e0 = roff[n];
    const int cnt = roff[n + 1] - e0;
    int i = 0;
    for (; i + 4 <= cnt; i += 4) {
        int b0 = esrc[e0 + i];
        int b1 = esrc[e0 + i + 1];
        int b2 = esrc[e0 + i + 2];
        int b3 = esrc[e0 + i + 3];
        uint4 u0 = *(const uint4*)(kvb + (size_t)b0 * KV_W + 8 * kl);
        uint4 u1 = *(const uint4*)(kvb + (size_t)b1 * KV_W + 8 * kl);
        uint4 u2 = *(const uint4*)(kvb + (size_t)b2 * KV_W + 8 * kl);
        uint4 u3 = *(const uint4*)(kvb + (size_t)b3 * KV_W + 8 * kl);
        ATTN_STEP(u0); ATTN_STEP(u1); ATTN_STEP(u2); ATTN_STEP(u3);
    }
    for (; i < cnt; ++i) {
        int b0 = esrc[e0 + i];
        uint4 u0 = *(const uint4*)(kvb + (size_t)b0 * KV_W + 8 * kl);
        ATTN_STEP(u0);
    }

    float inv = (s > 0.f) ? 1.f / s : 0.f;
    float4 o;
    o.x = acc.x * inv; o.y = acc.y * inv; o.z = acc.z * inv; o.w = acc.w * inv;
    // sum over heads (head bits of kl are bits 3,4; xor 8/16 stay in-half)
    o.x += __shfl_xor(o.x, 8);  o.y += __shfl_xor(o.y, 8);  o.z += __shfl_xor(o.z, 8);  o.w += __shfl_xor(o.w, 8);
    o.x += __shfl_xor(o.x, 16); o.y += __shfl_xor(o.y, 16); o.z += __shfl_xor(o.z, 16); o.w += __shfl_xor(o.w, 16);
    if (kl < 8) {
        float4 rr;
        rr.x = fmaxf(o.x * 0.25f + sk.x, 0.f);
        rr.y = fmaxf(o.y * 0.25f + sk.y, 0.f);
        rr.z = fmaxf(o.z * 0.25f + sk.z, 0.f);
        rr.w = fmaxf(o.w * 0.25f + sk.w, 0.f);
        int c0 = 4 * kl;
        if constexpr (FINAL) {
            int slot = (tid >> 6) * 2 + hw;          // 0..7 within block
            *(float4*)(&hbuf[slot][c0]) = rr;
        } else {
            ushort4 uh = {f2h(rr.x), f2h(rr.y), f2h(rr.z), f2h(rr.w)};
            *(ushort4*)(hf + (size_t)n * HID + c0) = uh;
        }
    }
    }
    if constexpr (FINAL) {
        __syncthreads();
        if (tid < 128) {
            int slot = tid >> 4;                     // node within block
            int j = tid & 15;
            int n2 = blockIdx.x * 8 + slot;
            if (n2 < NN) {
                float a = bout[j];
                #pragma unroll
                for (int k = 0; k < HID; ++k)
                    a += hbuf[slot][k] * Wout[k * OUT_DIM + j];
                outp[(size_t)n2 * OUT_DIM + j] = a;
            }
        }
    }
}

extern "C" void kernel_launch(void* const* d_in, const int* in_sizes, int n_in,
                              void* d_out, int out_size, void* d_ws, size_t ws_size,
                              hipStream_t stream) {
    const float* x  = (const float*)d_in[0];
    const int*   ei = (const int*)d_in[1];
    const float* l0w[8]; const float* l1w[8];
    for (int i = 0; i < 8; ++i) { l0w[i] = (const float*)d_in[2 + i]; l1w[i] = (const float*)d_in[10 + i]; }
    const float* Wout = (const float*)d_in[18];
    const float* bout = (const float*)d_in[19];
    float* out = (float*)d_out;

    // workspace layout
    float* ws = (float*)d_ws;
    float* sb   = ws;                           // NN*32 floats
    float* bp0  = sb + (size_t)NN * SB_W;       // 416
    float* bp1  = bp0 + COLS;                   // 416
    unsigned short* qbh  = (unsigned short*)(bp1 + COLS);    // NN*128 bf16
    unsigned short* kvb  = qbh + (size_t)NN * QBH_W;         // NN*256 bf16
    unsigned short* hf   = kvb + (size_t)NN * KV_W;          // NN*32 f16
    unsigned short* Wf0  = hf + (size_t)NN * HID;            // 4*26*64*8
    unsigned short* Wf1  = Wf0 + 4 * NTILE * 64 * 8;         // 1*26*64*8
    int* ibase  = (int*)(Wf1 + NTILE * 64 * 8);
    int* roff    = ibase;                       // NN+1
    int* esrc    = roff + NN + 1;               // EE
    int* cmat    = esrc + EE;                   // NCHUNK*NBIN (~200KB)
    int* omat    = cmat + NCHUNK * NBIN;        // NCHUNK*NBIN
    int* bbase   = omat + NCHUNK * NBIN;        // NBIN+1
    int2* pairs  = (int2*)(bbase + NBIN + 2);   // EE int2 (6.4 MB)

    // pack BOTH layers' weights in one launch
    pack_frag2<<<(5 * NTILE * 64 + 255) / 256, 256, 0, stream>>>(
        l0w[0], l0w[2], l0w[4], l0w[6], l0w[1], l0w[3], l0w[5], l0w[7],
        l1w[0], l1w[2], l1w[4], l1w[6], l1w[1], l1w[3], l1w[5], l1w[7],
        Wf0, bp0, Wf1, bp1);

    // ---- CSR build: atomic-free deterministic bin sort (5 kernels) ----
    chunk_hist<<<NCHUNK, 256, 0, stream>>>(ei, cmat);
    btot_scan<<<1, NBIN, 0, stream>>>(cmat, bbase);
    bin_prefix<<<NBIN, 256, 0, stream>>>(cmat, bbase, omat);
    bin_scatter<<<NCHUNK, 256, 0, stream>>>(ei, omat, pairs);
    bin_sort<<<NBIN, 256, 0, stream>>>(pairs, bbase, roff, esrc);

    const int gemm_blocks = (NN + 127) / 128;    // 782, one block = 128 rows x all tiles
    const int attn_waves = (NN + 1) / 2;         // one node per half-wave
    const int attn_blocks = (attn_waves * 64 + 255) / 256;   // 12500 (x8 = NN exactly)

    // layer 0: gemm reads X fp32 directly (in-staging f16 convert)
    gemm_mfma<4, true><<<gemm_blocks, 256, 0, stream>>>(
        x, Wf0, bp0, qbh, sb, kvb);
    fused_attn<false><<<attn_blocks, 256, 0, stream>>>(
        qbh, sb, kvb, roff, esrc, hf, (const float*)nullptr,
        (const float*)nullptr, (float*)nullptr);

    // layer 1: gemm reads h f16 plane; attn fuses the output linear
    gemm_mfma<1, false><<<gemm_blocks, 256, 0, stream>>>(
        hf, Wf1, bp1, qbh, sb, kvb);
    fused_attn<true><<<attn_blocks, 256, 0, stream>>>(
        qbh, sb, kvb, roff, esrc, (unsigned short*)nullptr, Wout, bout, out);
}